// Round 3
// baseline (184.233 us; speedup 1.0000x reference)
//
#include <hip/hip_runtime.h>

#define LROW 136   // padded LDS row stride in bf16 elements (128 + 8); 272 B rows
#define FSTR 72    // feat row stride in bf16 (64 K-cols + 8 pad); 144 B rows
#define DSTR 68    // dist row stride in f32 (was 64): quads land on distinct banks

typedef __bf16 bf16x8  __attribute__((ext_vector_type(8)));
typedef __bf16 bf16x2v __attribute__((ext_vector_type(2)));
typedef float  f32x4   __attribute__((ext_vector_type(4)));
typedef float  f32x2   __attribute__((ext_vector_type(2)));

#define MFMA16(a, b, c) __builtin_amdgcn_mfma_f32_16x16x32_bf16((a), (b), (c), 0, 0, 0)

__device__ __forceinline__ float bflo(unsigned v) { return __uint_as_float(v << 16); }
__device__ __forceinline__ float bfhi(unsigned v) { return __uint_as_float(v & 0xffff0000u); }

__device__ __forceinline__ unsigned short f2bf_u16(float f) {
  unsigned u = __float_as_uint(f);
  u += 0x7fffu + ((u >> 16) & 1u);
  return (unsigned short)(u >> 16);
}

// ---------------------------------------------------------------------------
// Kernel 1: fold linear layers into combined weight matrices (bf16, [n][k]
// transposed layout) + folded bias vectors (f32) + W1pT (pre_W1 transposed,
// bias folded as feature k=42, zero-padded to K=64). UNCHANGED from R11.
// ---------------------------------------------------------------------------
__global__ void combine_weights(
    const float* __restrict__ pre_W1, const float* __restrict__ pre_b1,
    const float* __restrict__ pre_W2, const float* __restrict__ msg_W1,
    const float* __restrict__ msg_W2, const float* __restrict__ post_W1,
    const float* __restrict__ post_W2, const float* __restrict__ out_W1,
    const float* __restrict__ out_W2, const float* __restrict__ pre_b2,
    const float* __restrict__ msg_b1, const float* __restrict__ msg_b2,
    const float* __restrict__ post_b1, const float* __restrict__ post_b2,
    const float* __restrict__ out_b1,
    unsigned short* __restrict__ WabT, unsigned short* __restrict__ WdT,
    unsigned short* __restrict__ WcT, unsigned short* __restrict__ WoT,
    unsigned short* __restrict__ Wo2T, unsigned short* __restrict__ W1pT,
    float* __restrict__ vecs)
{
  __shared__ float part[256];
  const int b = blockIdx.x;
  const int t = threadIdx.x;
  if (b < 320) {
    const int p  = b >> 6;
    const int kp = b & 63;
    const int k  = kp * 2 + (t >> 7);
    const int n  = t & 127;
    const float* L; const float* R; unsigned short* O;
    if (p == 0)      { L = pre_W2;  R = msg_W1;             O = WabT; }
    else if (p == 1) { L = pre_W2;  R = msg_W1 + 128*128;   O = WabT + 128*128; }
    else if (p == 2) { L = pre_W2;  R = post_W1 + 128*128;  O = WdT; }
    else if (p == 3) { L = msg_W2;  R = post_W1;            O = WcT; }
    else             { L = post_W2; R = out_W1;             O = WoT; }
    const float* Lr = L + k * 128;
    float a0 = 0.f, a1 = 0.f, a2 = 0.f, a3 = 0.f;
    #pragma unroll 8
    for (int m = 0; m < 128; m += 4) {
      a0 = fmaf(Lr[m + 0], R[(m + 0) * 128 + n], a0);
      a1 = fmaf(Lr[m + 1], R[(m + 1) * 128 + n], a1);
      a2 = fmaf(Lr[m + 2], R[(m + 2) * 128 + n], a2);
      a3 = fmaf(Lr[m + 3], R[(m + 3) * 128 + n], a3);
    }
    O[n * 128 + k] = f2bf_u16((a0 + a1) + (a2 + a3));
  } else if (b == 320) {
    // Wo2T transpose, w1d copy, W1pT build
    for (int idx = t; idx < 16 * 128; idx += 256) {
      int o = idx >> 7, k = idx & 127;
      Wo2T[o * 128 + k] = f2bf_u16(out_W2[k * 16 + o]);
    }
    if (t < 128) vecs[t] = msg_W1[256 * 128 + t];          // w1d
    for (int idx = t; idx < 128 * 64; idx += 256) {
      int n = idx >> 6, k = idx & 63;
      float v = (k < 42) ? pre_W1[k * 128 + n] : (k == 42 ? pre_b1[n] : 0.f);
      W1pT[n * 64 + k] = f2bf_u16(v);
    }
  } else {
    const int n = t & 127;
    const int h = t >> 7;
    float s = 0.f;
    if (b == 321) {            // cAB = pre_b2@(W1a+W1b) + msg_b1
      #pragma unroll 8
      for (int m = h * 64; m < h * 64 + 64; ++m)
        s = fmaf(pre_b2[m], msg_W1[m * 128 + n] + msg_W1[(128 + m) * 128 + n], s);
    } else if (b == 322) {     // cP = 7*msg_b2@P1a + pre_b2@P1b + post_b1
      #pragma unroll 8
      for (int m = h * 64; m < h * 64 + 64; ++m) {
        s = fmaf(7.f * msg_b2[m], post_W1[m * 128 + n], s);
        s = fmaf(pre_b2[m], post_W1[(128 + m) * 128 + n], s);
      }
    } else {                   // cO = 8*post_b2@out_W1 + out_b1
      #pragma unroll 8
      for (int m = h * 64; m < h * 64 + 64; ++m)
        s = fmaf(8.f * post_b2[m], out_W1[m * 128 + n], s);
    }
    part[t] = s;
    __syncthreads();
    if (t < 128) {
      float r = part[t] + part[t + 128];
      if (b == 321)      vecs[128 + t] = r + msg_b1[t];
      else if (b == 322) vecs[256 + t] = r + post_b1[t];
      else               vecs[384 + t] = r + out_b1[t];
    }
  }
}

// ---------------------------------------------------------------------------
// Kernel 2: fully fused RRN. R15: 8-WAVE BLOCKS (512 thr), same M=64 tile and
// 2048-block grid as R12 (56 us known-good). Waves split by ROW-HALF:
// wave (wr=w>>2, wc=w&3) owns rows wr*32..+31 of column slice wc*32..+31.
// Per-wave work halves; per-block LDS traffic / barriers / weight amortization
// unchanged -> resident waves/CU ~doubles (12->24 at 3 blocks/CU) to hide the
// latency that pins the kernel (R12-R14 all ~35% occ, all pipes <35% busy).
// launch_bounds(512,6) caps regs at 85 (worst-phase live ~70 -> no R14 spill).
// Also: dist stride 64->68 dwords and phase-4 quad column-window rotation
// (quad*16 cols) -- cuts the 4-way phase-4 bank conflicts to 2-way (free).
// ---------------------------------------------------------------------------
__global__ void __launch_bounds__(512, 6) rrn_main(
    const int* __restrict__ anchors, const int* __restrict__ n_jumps,
    const float* __restrict__ positions, const int* __restrict__ colors,
    const int* __restrict__ markers,
    const __bf16* __restrict__ W1pT,
    const __bf16* __restrict__ WabT, const __bf16* __restrict__ WdT,
    const __bf16* __restrict__ WcT, const __bf16* __restrict__ WoT,
    const __bf16* __restrict__ Wo2T, const float* __restrict__ vecs,
    const float* __restrict__ out_b2, float* __restrict__ out)
{
  __shared__ __align__(16) char smem[39040];
  // X [0,17408): phases 0-1: featL bf16[64][FSTR]. Phase 2+: Ab (A, then S).
  // Y [17408,34816): h1 (phases 1-2); Bb after h1-drain; Sph @17408 /
  //   hob @21760 (phases 5+).  dist f32[540] @34816 (stride 68); vec @36992.
  __bf16* featL = (__bf16*)(smem);
  __bf16* Ab    = (__bf16*)(smem);
  __bf16* h1    = (__bf16*)(smem + 17408);
  __bf16* Bb    = (__bf16*)(smem + 17408);
  __bf16* Sph   = (__bf16*)(smem + 17408);
  __bf16* hob   = (__bf16*)(smem + 21760);
  float*  dist  = (float*)(smem + 34816);
  float*  vec   = (float*)(smem + 36992);

  const int tid  = threadIdx.x;
  const int lane = tid & 63;
  const int w    = tid >> 6;      // wave 0..7
  const int wr   = w >> 2;        // row half 0..1 (rows wr*32 .. wr*32+31)
  const int wc   = w & 3;         // col slice 0..3
  const int l15  = lane & 15;
  const int quad = lane >> 4;
  const int colw = wc * 32;       // this wave's 32-col slice
  const int crow = colw + 2 * l15; // paired-col base: lane owns cols crow, crow+1
  const int rbase = wr * 32;      // this wave's M-row base
  const int g0   = blockIdx.x * 8;
  const int n0   = blockIdx.x * 64;

  // ---- phase 0: build feature rows (thread-private: no race), dist, vec
  if (tid < 64) {
    uint4* rp = (uint4*)&featL[tid * FSTR];   // 144 B row, 16B-aligned
    uint4 z4 = {0u, 0u, 0u, 0u};
    #pragma unroll
    for (int i = 0; i < 9; ++i) rp[i] = z4;
    int g = tid >> 3;
    float px = positions[(n0 + tid) * 2], py = positions[(n0 + tid) * 2 + 1];
    int c  = colors[n0 + tid], mk = markers[n0 + tid] - 8;
    int a  = anchors[g0 + g],  nj = n_jumps[g0 + g];
    __bf16* row = &featL[tid * FSTR];
    row[0] = (__bf16)px; row[1] = (__bf16)py;
    const __bf16 one = (__bf16)1.f;
    row[2 + c] = one; row[10 + mk] = one;
    row[18 + a] = one; row[34 + nj] = one;
    row[42] = one;                              // bias-as-feature
  }
  {
    int i = tid;   // 512 threads, 512 edges (8 graphs x 64)
    int g = i >> 6, ii = (i >> 3) & 7, jj = i & 7;
    const float* pa = positions + (n0 + g * 8 + ii) * 2;
    const float* pb = positions + (n0 + g * 8 + jj) * 2;
    float dx = pa[0] - pb[0], dy = pa[1] - pb[1];
    dist[g * DSTR + (i & 63)] = sqrtf(dx * dx + dy * dy);
  }
  vec[tid] = vecs[tid];
  __syncthreads();

  // ---- phase 1: h1 = relu(featL @ W1pT) via MFMA (M=64 split 2x32, N=128,
  //      K=64 padded). B-frag lanes load W1pT rows crow, crow+1.
  {
    f32x4 acch[2][2];
    f32x4 zero = {0.f, 0.f, 0.f, 0.f};
    acch[0][0] = zero; acch[0][1] = zero; acch[1][0] = zero; acch[1][1] = zero;
    #pragma unroll
    for (int kb = 0; kb < 64; kb += 32) {
      const int ko = kb + quad * 8;
      bf16x8 fa[2], fb[2];
      fa[0] = *(const bf16x8*)&featL[(rbase + l15) * FSTR + ko];
      fa[1] = *(const bf16x8*)&featL[(rbase + 16 + l15) * FSTR + ko];
      fb[0] = *(const bf16x8*)&W1pT[(crow) * 64 + ko];
      fb[1] = *(const bf16x8*)&W1pT[(crow + 1) * 64 + ko];
      #pragma unroll
      for (int mt = 0; mt < 2; ++mt) {
        acch[mt][0] = MFMA16(fa[mt], fb[0], acch[mt][0]);
        acch[mt][1] = MFMA16(fa[mt], fb[1], acch[mt][1]);
      }
    }
    #pragma unroll
    for (int mt = 0; mt < 2; ++mt)
      #pragma unroll
      for (int r = 0; r < 4; ++r) {
        bf16x2v o = { (__bf16)fmaxf(acch[mt][0][r], 0.f),
                      (__bf16)fmaxf(acch[mt][1][r], 0.f) };
        *(bf16x2v*)&h1[(rbase + mt * 16 + quad * 4 + r) * LROW + crow] = o;
      }
  }
  __syncthreads();   // featL reads done + h1 visible

  // ---- phase 2 pass A: A = h1 @ WabT[0:128] (own rows/cols), 16 accs,
  //      written immediately over dead featL.
  {
    f32x4 accA[2][2];
    f32x4 zero = {0.f, 0.f, 0.f, 0.f};
    accA[0][0] = zero; accA[0][1] = zero; accA[1][0] = zero; accA[1][1] = zero;
    #pragma unroll
    for (int kb = 0; kb < 128; kb += 32) {
      const int ko = kb + quad * 8;
      bf16x8 fa[2], fb[2];
      fa[0] = *(const bf16x8*)&h1[(rbase + l15) * LROW + ko];
      fa[1] = *(const bf16x8*)&h1[(rbase + 16 + l15) * LROW + ko];
      fb[0] = *(const bf16x8*)&WabT[(crow) * 128 + ko];
      fb[1] = *(const bf16x8*)&WabT[(crow + 1) * 128 + ko];
      accA[0][0] = MFMA16(fa[0], fb[0], accA[0][0]);
      accA[0][1] = MFMA16(fa[0], fb[1], accA[0][1]);
      accA[1][0] = MFMA16(fa[1], fb[0], accA[1][0]);
      accA[1][1] = MFMA16(fa[1], fb[1], accA[1][1]);
    }
    #pragma unroll
    for (int mt = 0; mt < 2; ++mt)
      #pragma unroll
      for (int r = 0; r < 4; ++r) {
        bf16x2v o = { (__bf16)accA[mt][0][r], (__bf16)accA[mt][1][r] };
        *(bf16x2v*)&Ab[(rbase + mt * 16 + quad * 4 + r) * LROW + crow] = o;
      }
  }

  // ---- phase 2 pass BD (fused, shared fa loads): B = h1 @ WabT[128:256],
  //      D = h1 @ WdT. Peak live accs: 16 (B) + 16 (D) = 32.
  //      accD stays live through phase 4 into phase 5.
  f32x4 accD[2][2];
  {
    f32x4 accB[2][2];
    f32x4 zero = {0.f, 0.f, 0.f, 0.f};
    accB[0][0] = zero; accB[0][1] = zero; accB[1][0] = zero; accB[1][1] = zero;
    accD[0][0] = zero; accD[0][1] = zero; accD[1][0] = zero; accD[1][1] = zero;
    #pragma unroll
    for (int kb = 0; kb < 128; kb += 32) {
      const int ko = kb + quad * 8;
      bf16x8 fa[2], fb[2], fd[2];
      fa[0] = *(const bf16x8*)&h1[(rbase + l15) * LROW + ko];
      fa[1] = *(const bf16x8*)&h1[(rbase + 16 + l15) * LROW + ko];
      fb[0] = *(const bf16x8*)&WabT[(128 + crow) * 128 + ko];
      fb[1] = *(const bf16x8*)&WabT[(128 + crow + 1) * 128 + ko];
      fd[0] = *(const bf16x8*)&WdT[(crow) * 128 + ko];
      fd[1] = *(const bf16x8*)&WdT[(crow + 1) * 128 + ko];
      accB[0][0] = MFMA16(fa[0], fb[0], accB[0][0]);
      accB[0][1] = MFMA16(fa[0], fb[1], accB[0][1]);
      accB[1][0] = MFMA16(fa[1], fb[0], accB[1][0]);
      accB[1][1] = MFMA16(fa[1], fb[1], accB[1][1]);
      accD[0][0] = MFMA16(fa[0], fd[0], accD[0][0]);
      accD[0][1] = MFMA16(fa[0], fd[1], accD[0][1]);
      accD[1][0] = MFMA16(fa[1], fd[0], accD[1][0]);
      accD[1][1] = MFMA16(fa[1], fd[1], accD[1][1]);
    }
    __syncthreads();   // h1 drain: all waves done reading Y before B overwrites it
    // write back B over the dead h1 region; own rows/cols only -> NO barrier.
    #pragma unroll
    for (int mt = 0; mt < 2; ++mt)
      #pragma unroll
      for (int r = 0; r < 4; ++r) {
        bf16x2v o = { (__bf16)accB[mt][0][r], (__bf16)accB[mt][1][r] };
        *(bf16x2v*)&Bb[(rbase + mt * 16 + quad * 4 + r) * LROW + crow] = o;
      }
  }

  // ---- phase 4: edges, OWN-ROWS/COLS mapping (no barrier since B write):
  //      wave (wr,wc): quad -> graph g = wr*4+quad (rows g*8.. are this
  //      wave's rows); lane l15 -> adjacent col pair, window ROTATED by
  //      quad*16 cols so the 4 quads hit disjoint bank halves (2-way, free).
  //      S[i] = sum_{j!=i} relu(A[i]+B[j]+d_ij*w1d+cAB), in place over A.
  {
    const int c0 = colw + ((((l15 & 8) << 1) + 2 * (l15 & 7) + quad * 16) & 31);
    const f32x2 wv = { vec[c0], vec[c0 + 1] };
    const f32x2 cv = { vec[128 + c0], vec[128 + c0 + 1] };
    const f32x2 z2 = {0.f, 0.f};
    const int g = wr * 4 + quad;
    f32x2 Bj[8];
    #pragma unroll
    for (int j = 0; j < 8; ++j) {
      unsigned vb = *(const unsigned*)&Bb[(g * 8 + j) * LROW + c0];
      Bj[j].x = bflo(vb); Bj[j].y = bfhi(vb);
    }
    #pragma unroll
    for (int i = 0; i < 8; ++i) {
      unsigned va = *(const unsigned*)&Ab[(g * 8 + i) * LROW + c0];
      f32x2 a = {bflo(va) + cv.x, bfhi(va) + cv.y};
      f32x2 s = z2;
      #pragma unroll
      for (int j = 0; j < 8; ++j) {
        if (j == i) continue;
        float d = dist[g * DSTR + i * 8 + j];
        f32x2 d2 = {d, d};
        f32x2 t = __builtin_elementwise_fma(d2, wv, Bj[j]) + a;
        s += __builtin_elementwise_max(t, z2);
      }
      unsigned o = (unsigned)f2bf_u16(s.x) | ((unsigned)f2bf_u16(s.y) << 16);
      *(unsigned*)&Ab[(g * 8 + i) * LROW + c0] = o;   // in-place S
    }
  }
  __syncthreads();   // S visible to all waves

  // ---- phase 5: ph = relu(S@Wc + D + cP); per-graph sum -> Sph rows 0..7
  //      (graph = wr*4 + mt*2 + hi), pad rows 8..15 zeroed.
  {
    const __bf16* Sb = Ab;
    #pragma unroll
    for (int kb = 0; kb < 128; kb += 32) {
      const int ko = kb + quad * 8;
      bf16x8 fa[2], fc[2];
      fa[0] = *(const bf16x8*)&Sb[(rbase + l15) * LROW + ko];
      fa[1] = *(const bf16x8*)&Sb[(rbase + 16 + l15) * LROW + ko];
      fc[0] = *(const bf16x8*)&WcT[(crow) * 128 + ko];
      fc[1] = *(const bf16x8*)&WcT[(crow + 1) * 128 + ko];
      accD[0][0] = MFMA16(fa[0], fc[0], accD[0][0]);
      accD[0][1] = MFMA16(fa[0], fc[1], accD[0][1]);
      accD[1][0] = MFMA16(fa[1], fc[0], accD[1][0]);
      accD[1][1] = MFMA16(fa[1], fc[1], accD[1][1]);
    }
    const f32x2 cpv = *(const f32x2*)&vec[256 + crow];
    #pragma unroll
    for (int mt = 0; mt < 2; ++mt) {
      f32x4 a0 = accD[mt][0];
      f32x4 a1 = accD[mt][1];
      float s0 = fmaxf(a0[0] + cpv.x, 0.f) + fmaxf(a0[1] + cpv.x, 0.f)
               + fmaxf(a0[2] + cpv.x, 0.f) + fmaxf(a0[3] + cpv.x, 0.f);
      float s1 = fmaxf(a1[0] + cpv.y, 0.f) + fmaxf(a1[1] + cpv.y, 0.f)
               + fmaxf(a1[2] + cpv.y, 0.f) + fmaxf(a1[3] + cpv.y, 0.f);
      s0 += __shfl_xor(s0, 16);
      s1 += __shfl_xor(s1, 16);
      int grow = wr * 4 + mt * 2 + (lane >= 32 ? 1 : 0);   // graph id 0..7
      if ((lane & 31) < 16) {
        bf16x2v o = { (__bf16)s0, (__bf16)s1 };
        *(bf16x2v*)&Sph[grow * LROW + crow] = o;
      } else {
        *(unsigned*)&Sph[(8 + grow) * LROW + crow] = 0u;  // zero pad rows
      }
    }
  }
  __syncthreads();

  // ---- phase 6: ho = relu(Sph @ WO + cO)  (M=16 tile: 8 graphs + 8 zero
  //      rows). Waves 0..3 (wr=0) only; their crow covers all 128 cols.
  if (w < 4) {
    f32x4 acco[2];
    f32x4 zero = {0.f, 0.f, 0.f, 0.f};
    acco[0] = zero; acco[1] = zero;
    #pragma unroll
    for (int kb = 0; kb < 128; kb += 32) {
      const int ko = kb + quad * 8;
      bf16x8 fa = *(const bf16x8*)&Sph[l15 * LROW + ko];
      bf16x8 fb0 = *(const bf16x8*)&WoT[(crow) * 128 + ko];
      bf16x8 fb1 = *(const bf16x8*)&WoT[(crow + 1) * 128 + ko];
      acco[0] = MFMA16(fa, fb0, acco[0]);
      acco[1] = MFMA16(fa, fb1, acco[1]);
    }
    const f32x2 cov = *(const f32x2*)&vec[384 + crow];
    #pragma unroll
    for (int r = 0; r < 4; ++r) {
      bf16x2v o = { (__bf16)fmaxf(acco[0][r] + cov.x, 0.f),
                    (__bf16)fmaxf(acco[1][r] + cov.y, 0.f) };
      *(bf16x2v*)&hob[(quad * 4 + r) * LROW + crow] = o;
    }
  }
  __syncthreads();

  // ---- phase 7: logits = ho @ out_W2 + out_b2  (wave 0 only) UNCHANGED
  if (w == 0) {
    f32x4 accf = {0.f, 0.f, 0.f, 0.f};
    #pragma unroll
    for (int kb = 0; kb < 128; kb += 32) {
      const int ko = kb + quad * 8;
      bf16x8 fa  = *(const bf16x8*)&hob[l15 * LROW + ko];
      bf16x8 fbv = *(const bf16x8*)&Wo2T[l15 * 128 + ko];
      accf = MFMA16(fa, fbv, accf);
    }
    if (quad < 2) {
      float b2 = out_b2[l15];
      #pragma unroll
      for (int r = 0; r < 4; ++r) {
        int row = quad * 4 + r;
        out[(g0 + row) * 16 + l15] = accf[r] + b2;
      }
    }
  }
}

extern "C" void kernel_launch(void* const* d_in, const int* in_sizes, int n_in,
                              void* d_out, int out_size, void* d_ws, size_t ws_size,
                              hipStream_t stream) {
  const int*   anchors   = (const int*)d_in[0];
  const int*   n_jumps   = (const int*)d_in[1];
  const float* positions = (const float*)d_in[2];
  const int*   colors    = (const int*)d_in[3];
  const int*   markers   = (const int*)d_in[4];
  const float* pre_W1  = (const float*)d_in[5];
  const float* pre_b1  = (const float*)d_in[6];
  const float* pre_W2  = (const float*)d_in[7];
  const float* pre_b2  = (const float*)d_in[8];
  const float* msg_W1  = (const float*)d_in[9];
  const float* msg_b1  = (const float*)d_in[10];
  const float* msg_W2  = (const float*)d_in[11];
  const float* msg_b2  = (const float*)d_in[12];
  const float* post_W1 = (const float*)d_in[13];
  const float* post_b1 = (const float*)d_in[14];
  const float* post_W2 = (const float*)d_in[15];
  const float* post_b2 = (const float*)d_in[16];
  const float* out_W1  = (const float*)d_in[17];
  const float* out_b1  = (const float*)d_in[18];
  const float* out_W2  = (const float*)d_in[19];
  const float* out_b2  = (const float*)d_in[20];

  char* ws = (char*)d_ws;
  unsigned short* WabT = (unsigned short*)(ws);            // [256][128] bf16
  unsigned short* WdT  = (unsigned short*)(ws + 65536);    // [128][128]
  unsigned short* WcT  = (unsigned short*)(ws + 98304);    // [128][128]
  unsigned short* WoT  = (unsigned short*)(ws + 131072);   // [128][128]
  unsigned short* Wo2T = (unsigned short*)(ws + 163840);   // [16][128]
  float*          vecs = (float*)(ws + 167936);            // 512 f32
  unsigned short* W1pT = (unsigned short*)(ws + 169984);   // [128][64] bf16

  const int BS = in_sizes[0];

  combine_weights<<<324, 256, 0, stream>>>(
      pre_W1, pre_b1, pre_W2, msg_W1, msg_W2, post_W1, post_W2, out_W1, out_W2,
      pre_b2, msg_b1, msg_b2, post_b1, post_b2, out_b1,
      WabT, WdT, WcT, WoT, Wo2T, W1pT, vecs);

  rrn_main<<<BS / 8, 512, 0, stream>>>(
      anchors, n_jumps, positions, colors, markers,
      (const __bf16*)W1pT,
      (const __bf16*)WabT, (const __bf16*)WdT, (const __bf16*)WcT,
      (const __bf16*)WoT, (const __bf16*)Wo2T, vecs, out_b2, (float*)d_out);
}

// Round 4
// 157.986 us; speedup vs baseline: 1.1661x; 1.1661x over previous
//
#include <hip/hip_runtime.h>

#define LROW 136   // padded LDS row stride in bf16 elements (128 + 8); 272 B rows
#define FSTR 72    // feat row stride in bf16 (64 K-cols + 8 pad); 144 B rows
#define DSTR 68    // dist row stride in f32: phase-4 quad groups land 2-way (free)

typedef __bf16 bf16x8  __attribute__((ext_vector_type(8)));
typedef __bf16 bf16x2v __attribute__((ext_vector_type(2)));
typedef float  f32x4   __attribute__((ext_vector_type(4)));
typedef float  f32x2   __attribute__((ext_vector_type(2)));

#define MFMA16(a, b, c) __builtin_amdgcn_mfma_f32_16x16x32_bf16((a), (b), (c), 0, 0, 0)

__device__ __forceinline__ float bflo(unsigned v) { return __uint_as_float(v << 16); }
__device__ __forceinline__ float bfhi(unsigned v) { return __uint_as_float(v & 0xffff0000u); }

__device__ __forceinline__ unsigned short f2bf_u16(float f) {
  unsigned u = __float_as_uint(f);
  u += 0x7fffu + ((u >> 16) & 1u);
  return (unsigned short)(u >> 16);
}

// ---------------------------------------------------------------------------
// Kernel 1: fold linear layers into combined weight matrices (bf16, [n][k]
// transposed layout) + folded bias vectors (f32) + W1pT (pre_W1 transposed,
// bias folded as feature k=42, zero-padded to K=64). UNCHANGED from R11.
// ---------------------------------------------------------------------------
__global__ void combine_weights(
    const float* __restrict__ pre_W1, const float* __restrict__ pre_b1,
    const float* __restrict__ pre_W2, const float* __restrict__ msg_W1,
    const float* __restrict__ msg_W2, const float* __restrict__ post_W1,
    const float* __restrict__ post_W2, const float* __restrict__ out_W1,
    const float* __restrict__ out_W2, const float* __restrict__ pre_b2,
    const float* __restrict__ msg_b1, const float* __restrict__ msg_b2,
    const float* __restrict__ post_b1, const float* __restrict__ post_b2,
    const float* __restrict__ out_b1,
    unsigned short* __restrict__ WabT, unsigned short* __restrict__ WdT,
    unsigned short* __restrict__ WcT, unsigned short* __restrict__ WoT,
    unsigned short* __restrict__ Wo2T, unsigned short* __restrict__ W1pT,
    float* __restrict__ vecs)
{
  __shared__ float part[256];
  const int b = blockIdx.x;
  const int t = threadIdx.x;
  if (b < 320) {
    const int p  = b >> 6;
    const int kp = b & 63;
    const int k  = kp * 2 + (t >> 7);
    const int n  = t & 127;
    const float* L; const float* R; unsigned short* O;
    if (p == 0)      { L = pre_W2;  R = msg_W1;             O = WabT; }
    else if (p == 1) { L = pre_W2;  R = msg_W1 + 128*128;   O = WabT + 128*128; }
    else if (p == 2) { L = pre_W2;  R = post_W1 + 128*128;  O = WdT; }
    else if (p == 3) { L = msg_W2;  R = post_W1;            O = WcT; }
    else             { L = post_W2; R = out_W1;             O = WoT; }
    const float* Lr = L + k * 128;
    float a0 = 0.f, a1 = 0.f, a2 = 0.f, a3 = 0.f;
    #pragma unroll 8
    for (int m = 0; m < 128; m += 4) {
      a0 = fmaf(Lr[m + 0], R[(m + 0) * 128 + n], a0);
      a1 = fmaf(Lr[m + 1], R[(m + 1) * 128 + n], a1);
      a2 = fmaf(Lr[m + 2], R[(m + 2) * 128 + n], a2);
      a3 = fmaf(Lr[m + 3], R[(m + 3) * 128 + n], a3);
    }
    O[n * 128 + k] = f2bf_u16((a0 + a1) + (a2 + a3));
  } else if (b == 320) {
    // Wo2T transpose, w1d copy, W1pT build
    for (int idx = t; idx < 16 * 128; idx += 256) {
      int o = idx >> 7, k = idx & 127;
      Wo2T[o * 128 + k] = f2bf_u16(out_W2[k * 16 + o]);
    }
    if (t < 128) vecs[t] = msg_W1[256 * 128 + t];          // w1d
    for (int idx = t; idx < 128 * 64; idx += 256) {
      int n = idx >> 6, k = idx & 63;
      float v = (k < 42) ? pre_W1[k * 128 + n] : (k == 42 ? pre_b1[n] : 0.f);
      W1pT[n * 64 + k] = f2bf_u16(v);
    }
  } else {
    const int n = t & 127;
    const int h = t >> 7;
    float s = 0.f;
    if (b == 321) {            // cAB = pre_b2@(W1a+W1b) + msg_b1
      #pragma unroll 8
      for (int m = h * 64; m < h * 64 + 64; ++m)
        s = fmaf(pre_b2[m], msg_W1[m * 128 + n] + msg_W1[(128 + m) * 128 + n], s);
    } else if (b == 322) {     // cP = 7*msg_b2@P1a + pre_b2@P1b + post_b1
      #pragma unroll 8
      for (int m = h * 64; m < h * 64 + 64; ++m) {
        s = fmaf(7.f * msg_b2[m], post_W1[m * 128 + n], s);
        s = fmaf(pre_b2[m], post_W1[(128 + m) * 128 + n], s);
      }
    } else {                   // cO = 8*post_b2@out_W1 + out_b1
      #pragma unroll 8
      for (int m = h * 64; m < h * 64 + 64; ++m)
        s = fmaf(8.f * post_b2[m], out_W1[m * 128 + n], s);
    }
    part[t] = s;
    __syncthreads();
    if (t < 128) {
      float r = part[t] + part[t + 128];
      if (b == 321)      vecs[128 + t] = r + msg_b1[t];
      else if (b == 322) vecs[256 + t] = r + post_b1[t];
      else               vecs[384 + t] = r + out_b1[t];
    }
  }
}

// ---------------------------------------------------------------------------
// Kernel 2: fully fused RRN. R16 = exact R12 decomposition (M=64, 4 waves,
// 2048 blocks -- the 56us known-good; R13/R14/R15 occupancy plays all
// regressed) with ONE change: phase 4 is REGISTER-RESIDENT. A,B stay in
// MFMA accumulators (acc1 kept live through pass 2); each lane assembles the
// partner quad's 4 B-rows via __shfl_xor(.,16) (same columns, other row
// half); S computed in regs via uniform 8-j loop minus the exact j==i term
// (d_ii=0). Only S is written to LDS. Deletes the A/B LDS round-trip (64
// b32 ops/lane, the 4-way-conflict source), and the h1-drain barrier (6->5).
// dist stride 64->68 (its 4-way quad conflict becomes 2-way = free).
// launch_bounds(256,3) matches measured 3 waves/SIMD; no spill incentive.
// ---------------------------------------------------------------------------
__global__ void __launch_bounds__(256, 3) rrn_main(
    const int* __restrict__ anchors, const int* __restrict__ n_jumps,
    const float* __restrict__ positions, const int* __restrict__ colors,
    const int* __restrict__ markers,
    const __bf16* __restrict__ W1pT,
    const __bf16* __restrict__ WabT, const __bf16* __restrict__ WdT,
    const __bf16* __restrict__ WcT, const __bf16* __restrict__ WoT,
    const __bf16* __restrict__ Wo2T, const float* __restrict__ vecs,
    const float* __restrict__ out_b2, float* __restrict__ out)
{
  __shared__ __align__(16) char smem[39040];
  // X [0,17408): phases 0-1: featL bf16[64][FSTR]. Phase 4+: S (bf16, LROW).
  // Y [17408,34816): h1 (phases 1-2); Sph @17408 / hob @21760 (phases 5+).
  // dist f32[8*DSTR] @34816; vec f32[512] @36992.
  __bf16* featL = (__bf16*)(smem);
  __bf16* Sb    = (__bf16*)(smem);                 // S lives over dead featL
  __bf16* h1    = (__bf16*)(smem + 17408);
  __bf16* Sph   = (__bf16*)(smem + 17408);
  __bf16* hob   = (__bf16*)(smem + 21760);
  float*  dist  = (float*)(smem + 34816);
  float*  vec   = (float*)(smem + 36992);

  const int tid  = threadIdx.x;
  const int lane = tid & 63;
  const int w    = tid >> 6;      // wave 0..3
  const int l15  = lane & 15;
  const int quad = lane >> 4;
  const int colw = w * 32;        // this wave's 32-col slice
  const int crow = colw + 2 * l15; // paired-col base: lane owns cols crow, crow+1
  const int g0   = blockIdx.x * 8;
  const int n0   = blockIdx.x * 64;

  // ---- phase 0: build feature rows (thread-private: no race), dist, vec
  if (tid < 64) {
    uint4* rp = (uint4*)&featL[tid * FSTR];   // 144 B row, 16B-aligned
    uint4 z4 = {0u, 0u, 0u, 0u};
    #pragma unroll
    for (int i = 0; i < 9; ++i) rp[i] = z4;
    int g = tid >> 3;
    float px = positions[(n0 + tid) * 2], py = positions[(n0 + tid) * 2 + 1];
    int c  = colors[n0 + tid], mk = markers[n0 + tid] - 8;
    int a  = anchors[g0 + g],  nj = n_jumps[g0 + g];
    __bf16* row = &featL[tid * FSTR];
    row[0] = (__bf16)px; row[1] = (__bf16)py;
    const __bf16 one = (__bf16)1.f;
    row[2 + c] = one; row[10 + mk] = one;
    row[18 + a] = one; row[34 + nj] = one;
    row[42] = one;                              // bias-as-feature
  }
  for (int i = tid; i < 512; i += 256) {
    int g = i >> 6, ii = (i >> 3) & 7, jj = i & 7;
    const float* pa = positions + (n0 + g * 8 + ii) * 2;
    const float* pb = positions + (n0 + g * 8 + jj) * 2;
    float dx = pa[0] - pb[0], dy = pa[1] - pb[1];
    dist[g * DSTR + (i & 63)] = sqrtf(dx * dx + dy * dy);
  }
  for (int i = tid; i < 512; i += 256) vec[i] = vecs[i];
  __syncthreads();

  // ---- phase 1: h1 = relu(featL @ W1pT) via MFMA (M=64, N=128, K=64 padded).
  //      B-frag lanes load W1pT rows crow, crow+1 -> adjacent output cols.
  {
    f32x4 acch[4][2];
    f32x4 zero = {0.f, 0.f, 0.f, 0.f};
    #pragma unroll
    for (int mt = 0; mt < 4; ++mt) { acch[mt][0] = zero; acch[mt][1] = zero; }
    #pragma unroll
    for (int kb = 0; kb < 64; kb += 32) {
      const int ko = kb + quad * 8;
      bf16x8 fa[4], fb[2];
      #pragma unroll
      for (int mt = 0; mt < 4; ++mt)
        fa[mt] = *(const bf16x8*)&featL[(mt * 16 + l15) * FSTR + ko];
      fb[0] = *(const bf16x8*)&W1pT[(crow) * 64 + ko];
      fb[1] = *(const bf16x8*)&W1pT[(crow + 1) * 64 + ko];
      #pragma unroll
      for (int mt = 0; mt < 4; ++mt) {
        acch[mt][0] = MFMA16(fa[mt], fb[0], acch[mt][0]);
        acch[mt][1] = MFMA16(fa[mt], fb[1], acch[mt][1]);
      }
    }
    #pragma unroll
    for (int mt = 0; mt < 4; ++mt)
      #pragma unroll
      for (int r = 0; r < 4; ++r) {
        bf16x2v o = { (__bf16)fmaxf(acch[mt][0][r], 0.f),
                      (__bf16)fmaxf(acch[mt][1][r], 0.f) };
        *(bf16x2v*)&h1[(mt * 16 + quad * 4 + r) * LROW + crow] = o;
      }
  }
  __syncthreads();   // featL reads done + h1 visible

  // ---- phase 2 pass 1: [A|B] cols crow,crow+1 (x A,B halves) = h1 @ WabT.
  //      acc1 STAYS IN REGISTERS through phase 4 (no LDS write-back).
  f32x4 acc1[4][4];   // nt 0,1 -> A cols crow,crow+1; nt 2,3 -> B cols crow,crow+1
  {
    f32x4 zero = {0.f, 0.f, 0.f, 0.f};
    #pragma unroll
    for (int mt = 0; mt < 4; ++mt)
      #pragma unroll
      for (int nt = 0; nt < 4; ++nt) acc1[mt][nt] = zero;
  }
  #pragma unroll
  for (int kb = 0; kb < 128; kb += 32) {
    const int ko = kb + quad * 8;
    bf16x8 fa[4], fb[4];
    #pragma unroll
    for (int mt = 0; mt < 4; ++mt)
      fa[mt] = *(const bf16x8*)&h1[(mt * 16 + l15) * LROW + ko];
    fb[0] = *(const bf16x8*)&WabT[(crow) * 128 + ko];
    fb[1] = *(const bf16x8*)&WabT[(crow + 1) * 128 + ko];
    fb[2] = *(const bf16x8*)&WabT[(128 + crow) * 128 + ko];
    fb[3] = *(const bf16x8*)&WabT[(128 + crow + 1) * 128 + ko];
    #pragma unroll
    for (int mt = 0; mt < 4; ++mt)
      #pragma unroll
      for (int nt = 0; nt < 4; ++nt)
        acc1[mt][nt] = MFMA16(fa[mt], fb[nt], acc1[mt][nt]);
  }

  // ---- phase 2 pass 2: D cols crow,crow+1 = h1 @ WdT (8 accs, live to ph5)
  f32x4 accD[4][2];
  {
    f32x4 zero = {0.f, 0.f, 0.f, 0.f};
    #pragma unroll
    for (int mt = 0; mt < 4; ++mt) { accD[mt][0] = zero; accD[mt][1] = zero; }
  }
  #pragma unroll
  for (int kb = 0; kb < 128; kb += 32) {
    const int ko = kb + quad * 8;
    bf16x8 fa[4], fd[2];
    #pragma unroll
    for (int mt = 0; mt < 4; ++mt)
      fa[mt] = *(const bf16x8*)&h1[(mt * 16 + l15) * LROW + ko];
    fd[0] = *(const bf16x8*)&WdT[(crow) * 128 + ko];
    fd[1] = *(const bf16x8*)&WdT[(crow + 1) * 128 + ko];
    #pragma unroll
    for (int mt = 0; mt < 4; ++mt) {
      accD[mt][0] = MFMA16(fa[mt], fd[0], accD[mt][0]);
      accD[mt][1] = MFMA16(fa[mt], fd[1], accD[mt][1]);
    }
  }
  // NO barrier, NO A/B write-back: phase 4 runs on registers.

  // ---- phase 4 (register-resident): lane owns cols crow,crow+1, rows
  //      mt*16+quad*4+rr (graph g=2mt+q1, within-graph row i=q0*4+rr).
  //      Partner quad (lane^16) holds the other 4 B-rows of the same graph,
  //      SAME columns -> shfl_xor(16) assembles all 8 B[j]. Uniform 8-j sum
  //      minus the exact j==i term (d_ii=0). S -> LDS over dead featL.
  {
    const f32x2 wv = { vec[crow], vec[crow + 1] };
    const f32x2 cv = { vec[128 + crow], vec[128 + crow + 1] };
    const int q0 = quad & 1;
    const int q1 = quad >> 1;
    const int jo = q0 * 4;          // own-half j base
    const int js = jo ^ 4;          // swapped-half j base
    #pragma unroll
    for (int mt = 0; mt < 4; ++mt) {
      const int g = 2 * mt + q1;
      float bo0[4], bo1[4], bs0[4], bs1[4];
      #pragma unroll
      for (int r = 0; r < 4; ++r) {
        bo0[r] = acc1[mt][2][r];
        bo1[r] = acc1[mt][3][r];
        bs0[r] = __shfl_xor(bo0[r], 16);
        bs1[r] = __shfl_xor(bo1[r], 16);
      }
      const float* dg = &dist[g * DSTR + jo * 8];   // row base for i = jo+rr
      #pragma unroll
      for (int rr = 0; rr < 4; ++rr) {
        const float* di = dg + rr * 8;
        float a0 = acc1[mt][0][rr] + cv.x;
        float a1 = acc1[mt][1][rr] + cv.y;
        // subtract the j==i term exactly (d=0 -> term = max(a+B[i],0))
        float s0 = -fmaxf(a0 + bo0[rr], 0.f);
        float s1 = -fmaxf(a1 + bo1[rr], 0.f);
        #pragma unroll
        for (int r = 0; r < 4; ++r) {
          float dox = di[jo + r];     // own half: j = jo + r
          float dsx = di[js + r];     // swapped half: j = js + r
          s0 += fmaxf(fmaf(dox, wv.x, bo0[r]) + a0, 0.f);
          s1 += fmaxf(fmaf(dox, wv.y, bo1[r]) + a1, 0.f);
          s0 += fmaxf(fmaf(dsx, wv.x, bs0[r]) + a0, 0.f);
          s1 += fmaxf(fmaf(dsx, wv.y, bs1[r]) + a1, 0.f);
        }
        unsigned o = (unsigned)f2bf_u16(s0) | ((unsigned)f2bf_u16(s1) << 16);
        *(unsigned*)&Sb[(mt * 16 + quad * 4 + rr) * LROW + crow] = o;
      }
    }
  }
  __syncthreads();   // S visible to all waves; h1 reads drained (pass 2 done)

  // ---- phase 5: ph = relu(S@Wc + D + cP); per-graph sum -> Sph (pad rows
  //      zeroed). fc rows crow,crow+1 match accD's col assignment.
  {
    #pragma unroll
    for (int kb = 0; kb < 128; kb += 32) {
      const int ko = kb + quad * 8;
      bf16x8 fa[4], fc[2];
      #pragma unroll
      for (int mt = 0; mt < 4; ++mt)
        fa[mt] = *(const bf16x8*)&Sb[(mt * 16 + l15) * LROW + ko];
      fc[0] = *(const bf16x8*)&WcT[(crow) * 128 + ko];
      fc[1] = *(const bf16x8*)&WcT[(crow + 1) * 128 + ko];
      #pragma unroll
      for (int mt = 0; mt < 4; ++mt) {
        accD[mt][0] = MFMA16(fa[mt], fc[0], accD[mt][0]);
        accD[mt][1] = MFMA16(fa[mt], fc[1], accD[mt][1]);
      }
    }
    const f32x2 cpv = *(const f32x2*)&vec[256 + crow];
    #pragma unroll
    for (int mt = 0; mt < 4; ++mt) {
      f32x4 a0 = accD[mt][0];
      f32x4 a1 = accD[mt][1];
      float s0 = fmaxf(a0[0] + cpv.x, 0.f) + fmaxf(a0[1] + cpv.x, 0.f)
               + fmaxf(a0[2] + cpv.x, 0.f) + fmaxf(a0[3] + cpv.x, 0.f);
      float s1 = fmaxf(a1[0] + cpv.y, 0.f) + fmaxf(a1[1] + cpv.y, 0.f)
               + fmaxf(a1[2] + cpv.y, 0.f) + fmaxf(a1[3] + cpv.y, 0.f);
      s0 += __shfl_xor(s0, 16);
      s1 += __shfl_xor(s1, 16);
      int grow = mt * 2 + (lane >= 32 ? 1 : 0);
      if ((lane & 31) < 16) {
        bf16x2v o = { (__bf16)s0, (__bf16)s1 };
        *(bf16x2v*)&Sph[grow * LROW + crow] = o;
      } else {
        *(unsigned*)&Sph[(8 + grow) * LROW + crow] = 0u;  // zero pad rows
      }
    }
  }
  __syncthreads();

  // ---- phase 6: ho = relu(Sph @ WO + cO)  (M=16 tile: 8 graphs + 8 zero rows)
  {
    f32x4 acco[2];
    f32x4 zero = {0.f, 0.f, 0.f, 0.f};
    acco[0] = zero; acco[1] = zero;
    #pragma unroll
    for (int kb = 0; kb < 128; kb += 32) {
      const int ko = kb + quad * 8;
      bf16x8 fa = *(const bf16x8*)&Sph[l15 * LROW + ko];
      bf16x8 fb0 = *(const bf16x8*)&WoT[(crow) * 128 + ko];
      bf16x8 fb1 = *(const bf16x8*)&WoT[(crow + 1) * 128 + ko];
      acco[0] = MFMA16(fa, fb0, acco[0]);
      acco[1] = MFMA16(fa, fb1, acco[1]);
    }
    const f32x2 cov = *(const f32x2*)&vec[384 + crow];
    #pragma unroll
    for (int r = 0; r < 4; ++r) {
      bf16x2v o = { (__bf16)fmaxf(acco[0][r] + cov.x, 0.f),
                    (__bf16)fmaxf(acco[1][r] + cov.y, 0.f) };
      *(bf16x2v*)&hob[(quad * 4 + r) * LROW + crow] = o;
    }
  }
  __syncthreads();

  // ---- phase 7: logits = ho @ out_W2 + out_b2  (wave 0 only) UNCHANGED
  if (w == 0) {
    f32x4 accf = {0.f, 0.f, 0.f, 0.f};
    #pragma unroll
    for (int kb = 0; kb < 128; kb += 32) {
      const int ko = kb + quad * 8;
      bf16x8 fa  = *(const bf16x8*)&hob[l15 * LROW + ko];
      bf16x8 fbv = *(const bf16x8*)&Wo2T[l15 * 128 + ko];
      accf = MFMA16(fa, fbv, accf);
    }
    if (quad < 2) {
      float b2 = out_b2[l15];
      #pragma unroll
      for (int r = 0; r < 4; ++r) {
        int row = quad * 4 + r;
        out[(g0 + row) * 16 + l15] = accf[r] + b2;
      }
    }
  }
}

extern "C" void kernel_launch(void* const* d_in, const int* in_sizes, int n_in,
                              void* d_out, int out_size, void* d_ws, size_t ws_size,
                              hipStream_t stream) {
  const int*   anchors   = (const int*)d_in[0];
  const int*   n_jumps   = (const int*)d_in[1];
  const float* positions = (const float*)d_in[2];
  const int*   colors    = (const int*)d_in[3];
  const int*   markers   = (const int*)d_in[4];
  const float* pre_W1  = (const float*)d_in[5];
  const float* pre_b1  = (const float*)d_in[6];
  const float* pre_W2  = (const float*)d_in[7];
  const float* pre_b2  = (const float*)d_in[8];
  const float* msg_W1  = (const float*)d_in[9];
  const float* msg_b1  = (const float*)d_in[10];
  const float* msg_W2  = (const float*)d_in[11];
  const float* msg_b2  = (const float*)d_in[12];
  const float* post_W1 = (const float*)d_in[13];
  const float* post_b1 = (const float*)d_in[14];
  const float* post_W2 = (const float*)d_in[15];
  const float* post_b2 = (const float*)d_in[16];
  const float* out_W1  = (const float*)d_in[17];
  const float* out_b1  = (const float*)d_in[18];
  const float* out_W2  = (const float*)d_in[19];
  const float* out_b2  = (const float*)d_in[20];

  char* ws = (char*)d_ws;
  unsigned short* WabT = (unsigned short*)(ws);            // [256][128] bf16
  unsigned short* WdT  = (unsigned short*)(ws + 65536);    // [128][128]
  unsigned short* WcT  = (unsigned short*)(ws + 98304);    // [128][128]
  unsigned short* WoT  = (unsigned short*)(ws + 131072);   // [128][128]
  unsigned short* Wo2T = (unsigned short*)(ws + 163840);   // [16][128]
  float*          vecs = (float*)(ws + 167936);            // 512 f32
  unsigned short* W1pT = (unsigned short*)(ws + 169984);   // [128][64] bf16

  const int BS = in_sizes[0];

  combine_weights<<<324, 256, 0, stream>>>(
      pre_W1, pre_b1, pre_W2, msg_W1, msg_W2, post_W1, post_W2, out_W1, out_W2,
      pre_b2, msg_b1, msg_b2, post_b1, post_b2, out_b1,
      WabT, WdT, WcT, WoT, Wo2T, W1pT, vecs);

  rrn_main<<<BS / 8, 256, 0, stream>>>(
      anchors, n_jumps, positions, colors, markers,
      (const __bf16*)W1pT,
      (const __bf16*)WabT, (const __bf16*)WdT, (const __bf16*)WcT,
      (const __bf16*)WoT, (const __bf16*)Wo2T, vecs, out_b2, (float*)d_out);
}

// Round 6
// 154.031 us; speedup vs baseline: 1.1961x; 1.0257x over previous
//
#include <hip/hip_runtime.h>

#define LROW 136   // padded LDS row stride in bf16 elements (128 + 8); 272 B rows
#define FSTR 72    // feat row stride in bf16 (64 K-cols + 8 pad); 144 B rows
#define DSTR 68    // dist row stride in f16x2 units: quad dist reads land <=2-way

typedef __bf16 bf16x8  __attribute__((ext_vector_type(8)));
typedef __bf16 bf16x2v __attribute__((ext_vector_type(2)));
typedef float  f32x4   __attribute__((ext_vector_type(4)));
typedef float  f32x2   __attribute__((ext_vector_type(2)));
typedef __fp16 f16x2   __attribute__((ext_vector_type(2)));  // matches cvt_pkrtz return

#define MFMA16(a, b, c) __builtin_amdgcn_mfma_f32_16x16x32_bf16((a), (b), (c), 0, 0, 0)

__device__ __forceinline__ float bflo(unsigned v) { return __uint_as_float(v << 16); }
__device__ __forceinline__ float bfhi(unsigned v) { return __uint_as_float(v & 0xffff0000u); }

__device__ __forceinline__ unsigned short f2bf_u16(float f) {
  unsigned u = __float_as_uint(f);
  u += 0x7fffu + ((u >> 16) & 1u);
  return (unsigned short)(u >> 16);
}

// ---------------------------------------------------------------------------
// Kernel 1: fold linear layers into combined weight matrices (bf16, [n][k]
// transposed layout) + folded bias vectors (f32) + W1pT (pre_W1 transposed,
// bias folded as feature k=42, zero-padded to K=64). UNCHANGED from R11.
// ---------------------------------------------------------------------------
__global__ void combine_weights(
    const float* __restrict__ pre_W1, const float* __restrict__ pre_b1,
    const float* __restrict__ pre_W2, const float* __restrict__ msg_W1,
    const float* __restrict__ msg_W2, const float* __restrict__ post_W1,
    const float* __restrict__ post_W2, const float* __restrict__ out_W1,
    const float* __restrict__ out_W2, const float* __restrict__ pre_b2,
    const float* __restrict__ msg_b1, const float* __restrict__ msg_b2,
    const float* __restrict__ post_b1, const float* __restrict__ post_b2,
    const float* __restrict__ out_b1,
    unsigned short* __restrict__ WabT, unsigned short* __restrict__ WdT,
    unsigned short* __restrict__ WcT, unsigned short* __restrict__ WoT,
    unsigned short* __restrict__ Wo2T, unsigned short* __restrict__ W1pT,
    float* __restrict__ vecs)
{
  __shared__ float part[256];
  const int b = blockIdx.x;
  const int t = threadIdx.x;
  if (b < 320) {
    const int p  = b >> 6;
    const int kp = b & 63;
    const int k  = kp * 2 + (t >> 7);
    const int n  = t & 127;
    const float* L; const float* R; unsigned short* O;
    if (p == 0)      { L = pre_W2;  R = msg_W1;             O = WabT; }
    else if (p == 1) { L = pre_W2;  R = msg_W1 + 128*128;   O = WabT + 128*128; }
    else if (p == 2) { L = pre_W2;  R = post_W1 + 128*128;  O = WdT; }
    else if (p == 3) { L = msg_W2;  R = post_W1;            O = WcT; }
    else             { L = post_W2; R = out_W1;             O = WoT; }
    const float* Lr = L + k * 128;
    float a0 = 0.f, a1 = 0.f, a2 = 0.f, a3 = 0.f;
    #pragma unroll 8
    for (int m = 0; m < 128; m += 4) {
      a0 = fmaf(Lr[m + 0], R[(m + 0) * 128 + n], a0);
      a1 = fmaf(Lr[m + 1], R[(m + 1) * 128 + n], a1);
      a2 = fmaf(Lr[m + 2], R[(m + 2) * 128 + n], a2);
      a3 = fmaf(Lr[m + 3], R[(m + 3) * 128 + n], a3);
    }
    O[n * 128 + k] = f2bf_u16((a0 + a1) + (a2 + a3));
  } else if (b == 320) {
    // Wo2T transpose, w1d copy, W1pT build
    for (int idx = t; idx < 16 * 128; idx += 256) {
      int o = idx >> 7, k = idx & 127;
      Wo2T[o * 128 + k] = f2bf_u16(out_W2[k * 16 + o]);
    }
    if (t < 128) vecs[t] = msg_W1[256 * 128 + t];          // w1d
    for (int idx = t; idx < 128 * 64; idx += 256) {
      int n = idx >> 6, k = idx & 63;
      float v = (k < 42) ? pre_W1[k * 128 + n] : (k == 42 ? pre_b1[n] : 0.f);
      W1pT[n * 64 + k] = f2bf_u16(v);
    }
  } else {
    const int n = t & 127;
    const int h = t >> 7;
    float s = 0.f;
    if (b == 321) {            // cAB = pre_b2@(W1a+W1b) + msg_b1
      #pragma unroll 8
      for (int m = h * 64; m < h * 64 + 64; ++m)
        s = fmaf(pre_b2[m], msg_W1[m * 128 + n] + msg_W1[(128 + m) * 128 + n], s);
    } else if (b == 322) {     // cP = 7*msg_b2@P1a + pre_b2@P1b + post_b1
      #pragma unroll 8
      for (int m = h * 64; m < h * 64 + 64; ++m) {
        s = fmaf(7.f * msg_b2[m], post_W1[m * 128 + n], s);
        s = fmaf(pre_b2[m], post_W1[(128 + m) * 128 + n], s);
      }
    } else {                   // cO = 8*post_b2@out_W1 + out_b1
      #pragma unroll 8
      for (int m = h * 64; m < h * 64 + 64; ++m)
        s = fmaf(8.f * post_b2[m], out_W1[m * 128 + n], s);
    }
    part[t] = s;
    __syncthreads();
    if (t < 128) {
      float r = part[t] + part[t + 128];
      if (b == 321)      vecs[128 + t] = r + msg_b1[t];
      else if (b == 322) vecs[256 + t] = r + post_b1[t];
      else               vecs[384 + t] = r + out_b1[t];
    }
  }
}

// ---------------------------------------------------------------------------
// Kernel 2: fully fused RRN. R18 = R17 with the f16x2 typedef fixed (__fp16
// ext-vector to match __builtin_amdgcn_cvt_pkrtz's return type). Structure =
// EXACT R12 (56us known-good: M=64, 4 waves, 2048 blocks, A/B via LDS,
// launch_bounds(256,4)); two in-place phase-4 changes:
// (1) PACKED-F16 edge math: dist stored as {d,d} half2 in phase 0; inner
//     loop = v_pk_fma/pk_add/pk_max on f16x2 -> 4 ops per (i,j) col-pair
//     instead of 8 scalar f32 ops.
// (2) ROW-ROTATION m=4*(quad&1): i_act=i^m, j_act=j^m (B-slots and d-cols
//     rotate together -> diagonal skip stays compile-time). Quads {1,3} hit
//     banks +16 vs {0,2} -> 32 banks tiled, 2 lanes/bank = free (was 4-way).
// ---------------------------------------------------------------------------
__global__ void __launch_bounds__(256, 4) rrn_main(
    const int* __restrict__ anchors, const int* __restrict__ n_jumps,
    const float* __restrict__ positions, const int* __restrict__ colors,
    const int* __restrict__ markers,
    const __bf16* __restrict__ W1pT,
    const __bf16* __restrict__ WabT, const __bf16* __restrict__ WdT,
    const __bf16* __restrict__ WcT, const __bf16* __restrict__ WoT,
    const __bf16* __restrict__ Wo2T, const float* __restrict__ vecs,
    const float* __restrict__ out_b2, float* __restrict__ out)
{
  __shared__ __align__(16) char smem[39040];
  // X [0,17408): phases 0-1: featL bf16[64][FSTR]. Phase 2+: Ab (A, then S).
  // Y [17408,34816): h1 (phases 1-2); Bb after h1-drain; Sph @17408 /
  //   hob @21760 (phases 5+).  distH f16x2[8*DSTR] @34816; vec f32 @36992.
  __bf16* featL = (__bf16*)(smem);
  __bf16* Ab    = (__bf16*)(smem);
  __bf16* h1    = (__bf16*)(smem + 17408);
  __bf16* Bb    = (__bf16*)(smem + 17408);
  __bf16* Sph   = (__bf16*)(smem + 17408);
  __bf16* hob   = (__bf16*)(smem + 21760);
  f16x2*  distH = (f16x2*)(smem + 34816);
  float*  vec   = (float*)(smem + 36992);

  const int tid  = threadIdx.x;
  const int lane = tid & 63;
  const int w    = tid >> 6;      // wave 0..3
  const int l15  = lane & 15;
  const int quad = lane >> 4;
  const int colw = w * 32;        // this wave's 32-col slice
  const int crow = colw + 2 * l15; // paired-col base: lane owns cols crow, crow+1
  const int g0   = blockIdx.x * 8;
  const int n0   = blockIdx.x * 64;

  // ---- phase 0: build feature rows (thread-private: no race), dist, vec
  if (tid < 64) {
    uint4* rp = (uint4*)&featL[tid * FSTR];   // 144 B row, 16B-aligned
    uint4 z4 = {0u, 0u, 0u, 0u};
    #pragma unroll
    for (int i = 0; i < 9; ++i) rp[i] = z4;
    int g = tid >> 3;
    float px = positions[(n0 + tid) * 2], py = positions[(n0 + tid) * 2 + 1];
    int c  = colors[n0 + tid], mk = markers[n0 + tid] - 8;
    int a  = anchors[g0 + g],  nj = n_jumps[g0 + g];
    __bf16* row = &featL[tid * FSTR];
    row[0] = (__bf16)px; row[1] = (__bf16)py;
    const __bf16 one = (__bf16)1.f;
    row[2 + c] = one; row[10 + mk] = one;
    row[18 + a] = one; row[34 + nj] = one;
    row[42] = one;                              // bias-as-feature
  }
  for (int i = tid; i < 512; i += 256) {
    int g = i >> 6, ii = (i >> 3) & 7, jj = i & 7;
    const float* pa = positions + (n0 + g * 8 + ii) * 2;
    const float* pb = positions + (n0 + g * 8 + jj) * 2;
    float dx = pa[0] - pb[0], dy = pa[1] - pb[1];
    float d = sqrtf(dx * dx + dy * dy);
    distH[g * DSTR + (i & 63)] = __builtin_amdgcn_cvt_pkrtz(d, d);
  }
  for (int i = tid; i < 512; i += 256) vec[i] = vecs[i];
  __syncthreads();

  // ---- phase 1: h1 = relu(featL @ W1pT) via MFMA (M=64, N=128, K=64 padded).
  //      B-frag lanes load W1pT rows crow, crow+1 -> adjacent output cols.
  {
    f32x4 acch[4][2];
    f32x4 zero = {0.f, 0.f, 0.f, 0.f};
    #pragma unroll
    for (int mt = 0; mt < 4; ++mt) { acch[mt][0] = zero; acch[mt][1] = zero; }
    #pragma unroll
    for (int kb = 0; kb < 64; kb += 32) {
      const int ko = kb + quad * 8;
      bf16x8 fa[4], fb[2];
      #pragma unroll
      for (int mt = 0; mt < 4; ++mt)
        fa[mt] = *(const bf16x8*)&featL[(mt * 16 + l15) * FSTR + ko];
      fb[0] = *(const bf16x8*)&W1pT[(crow) * 64 + ko];
      fb[1] = *(const bf16x8*)&W1pT[(crow + 1) * 64 + ko];
      #pragma unroll
      for (int mt = 0; mt < 4; ++mt) {
        acch[mt][0] = MFMA16(fa[mt], fb[0], acch[mt][0]);
        acch[mt][1] = MFMA16(fa[mt], fb[1], acch[mt][1]);
      }
    }
    #pragma unroll
    for (int mt = 0; mt < 4; ++mt)
      #pragma unroll
      for (int r = 0; r < 4; ++r) {
        bf16x2v o = { (__bf16)fmaxf(acch[mt][0][r], 0.f),
                      (__bf16)fmaxf(acch[mt][1][r], 0.f) };
        *(bf16x2v*)&h1[(mt * 16 + quad * 4 + r) * LROW + crow] = o;
      }
  }
  __syncthreads();   // featL reads done + h1 visible

  // ---- phase 2 pass 1: [A|B] cols crow,crow+1 (x A,B halves) = h1 @ WabT
  f32x4 acc1[4][4];   // nt 0,1 -> A cols crow,crow+1; nt 2,3 -> B cols crow,crow+1
  {
    f32x4 zero = {0.f, 0.f, 0.f, 0.f};
    #pragma unroll
    for (int mt = 0; mt < 4; ++mt)
      #pragma unroll
      for (int nt = 0; nt < 4; ++nt) acc1[mt][nt] = zero;
  }
  #pragma unroll
  for (int kb = 0; kb < 128; kb += 32) {
    const int ko = kb + quad * 8;
    bf16x8 fa[4], fb[4];
    #pragma unroll
    for (int mt = 0; mt < 4; ++mt)
      fa[mt] = *(const bf16x8*)&h1[(mt * 16 + l15) * LROW + ko];
    fb[0] = *(const bf16x8*)&WabT[(crow) * 128 + ko];
    fb[1] = *(const bf16x8*)&WabT[(crow + 1) * 128 + ko];
    fb[2] = *(const bf16x8*)&WabT[(128 + crow) * 128 + ko];
    fb[3] = *(const bf16x8*)&WabT[(128 + crow + 1) * 128 + ko];
    #pragma unroll
    for (int mt = 0; mt < 4; ++mt)
      #pragma unroll
      for (int nt = 0; nt < 4; ++nt)
        acc1[mt][nt] = MFMA16(fa[mt], fb[nt], acc1[mt][nt]);
  }
  // write back A now (featL dead since post-phase-1 barrier); own cols only.
  #pragma unroll
  for (int mt = 0; mt < 4; ++mt)
    #pragma unroll
    for (int r = 0; r < 4; ++r) {
      bf16x2v o = { (__bf16)acc1[mt][0][r], (__bf16)acc1[mt][1][r] };
      *(bf16x2v*)&Ab[(mt * 16 + quad * 4 + r) * LROW + crow] = o;
    }

  // ---- phase 2 pass 2: D cols crow,crow+1 = h1 @ WdT (8 accs, live to ph5)
  f32x4 accD[4][2];
  {
    f32x4 zero = {0.f, 0.f, 0.f, 0.f};
    #pragma unroll
    for (int mt = 0; mt < 4; ++mt) { accD[mt][0] = zero; accD[mt][1] = zero; }
  }
  #pragma unroll
  for (int kb = 0; kb < 128; kb += 32) {
    const int ko = kb + quad * 8;
    bf16x8 fa[4], fd[2];
    #pragma unroll
    for (int mt = 0; mt < 4; ++mt)
      fa[mt] = *(const bf16x8*)&h1[(mt * 16 + l15) * LROW + ko];
    fd[0] = *(const bf16x8*)&WdT[(crow) * 128 + ko];
    fd[1] = *(const bf16x8*)&WdT[(crow + 1) * 128 + ko];
    #pragma unroll
    for (int mt = 0; mt < 4; ++mt) {
      accD[mt][0] = MFMA16(fa[mt], fd[0], accD[mt][0]);
      accD[mt][1] = MFMA16(fa[mt], fd[1], accD[mt][1]);
    }
  }
  __syncthreads();   // h1 drain: all waves done reading Y before B overwrites it
  // write back B over the dead h1 region; own cols only -> NO barrier after.
  #pragma unroll
  for (int mt = 0; mt < 4; ++mt)
    #pragma unroll
    for (int r = 0; r < 4; ++r) {
      bf16x2v o = { (__bf16)acc1[mt][2][r], (__bf16)acc1[mt][3][r] };
      *(bf16x2v*)&Bb[(mt * 16 + quad * 4 + r) * LROW + crow] = o;
    }

  // ---- phase 4: edges, own-column mapping (no barrier since B write).
  //      Packed f16x2 math; row-rotation m=4*(quad&1): slot (i,j) maps to
  //      actual rows (i^m, j^m) -> quads {1,3} +16 banks vs {0,2} (2-way,
  //      free). Diagonal skip j==i is slot==slot -> compile-time uniform.
  //      S[i] = sum_{j!=i} relu(A[i]+B[j]+d_ij*w1d+cAB), in place over A.
  {
    const int c0 = colw + ((l15 & 8) << 1) + 2 * (l15 & 7);  // adjacent pair
    const int m  = (quad & 1) << 2;                          // row rotation
    const f16x2 zh = {(__fp16)0.f, (__fp16)0.f};
    const f16x2 wv = __builtin_amdgcn_cvt_pkrtz(vec[c0], vec[c0 + 1]);
    const float cvx = vec[128 + c0], cvy = vec[128 + c0 + 1];
    #pragma unroll
    for (int gi = 0; gi < 2; ++gi) {
      const int g8 = (2 * quad + gi) * 8;
      const f16x2* dg = &distH[(2 * quad + gi) * DSTR];
      f16x2 Bj[8];
      #pragma unroll
      for (int j = 0; j < 8; ++j) {
        unsigned vb = *(const unsigned*)&Bb[(g8 + (j ^ m)) * LROW + c0];
        Bj[j] = __builtin_amdgcn_cvt_pkrtz(bflo(vb), bfhi(vb));
      }
      #pragma unroll
      for (int i = 0; i < 8; ++i) {
        const int ia = i ^ m;
        unsigned va = *(const unsigned*)&Ab[(g8 + ia) * LROW + c0];
        f16x2 a = __builtin_amdgcn_cvt_pkrtz(bflo(va) + cvx, bfhi(va) + cvy);
        const f16x2* di = dg + ia * 8;
        f16x2 s = zh;
        #pragma unroll
        for (int j = 0; j < 8; ++j) {
          if (j == i) continue;   // slot diagonal == actual diagonal
          f16x2 t = __builtin_elementwise_fma(di[j ^ m], wv, Bj[j]) + a;
          s = s + __builtin_elementwise_max(t, zh);
        }
        unsigned o = (unsigned)f2bf_u16((float)s.x) |
                     ((unsigned)f2bf_u16((float)s.y) << 16);
        *(unsigned*)&Ab[(g8 + ia) * LROW + c0] = o;   // in-place S
      }
    }
  }
  __syncthreads();   // S visible to all waves

  // ---- phase 5: ph = relu(S@Wc + D + cP); per-graph sum -> Sph (pad rows
  //      zeroed). fc rows crow,crow+1 match accD's col assignment.
  {
    const __bf16* Sb = Ab;
    #pragma unroll
    for (int kb = 0; kb < 128; kb += 32) {
      const int ko = kb + quad * 8;
      bf16x8 fa[4], fc[2];
      #pragma unroll
      for (int mt = 0; mt < 4; ++mt)
        fa[mt] = *(const bf16x8*)&Sb[(mt * 16 + l15) * LROW + ko];
      fc[0] = *(const bf16x8*)&WcT[(crow) * 128 + ko];
      fc[1] = *(const bf16x8*)&WcT[(crow + 1) * 128 + ko];
      #pragma unroll
      for (int mt = 0; mt < 4; ++mt) {
        accD[mt][0] = MFMA16(fa[mt], fc[0], accD[mt][0]);
        accD[mt][1] = MFMA16(fa[mt], fc[1], accD[mt][1]);
      }
    }
    const f32x2 cpv = *(const f32x2*)&vec[256 + crow];
    #pragma unroll
    for (int mt = 0; mt < 4; ++mt) {
      f32x4 a0 = accD[mt][0];
      f32x4 a1 = accD[mt][1];
      float s0 = fmaxf(a0[0] + cpv.x, 0.f) + fmaxf(a0[1] + cpv.x, 0.f)
               + fmaxf(a0[2] + cpv.x, 0.f) + fmaxf(a0[3] + cpv.x, 0.f);
      float s1 = fmaxf(a1[0] + cpv.y, 0.f) + fmaxf(a1[1] + cpv.y, 0.f)
               + fmaxf(a1[2] + cpv.y, 0.f) + fmaxf(a1[3] + cpv.y, 0.f);
      s0 += __shfl_xor(s0, 16);
      s1 += __shfl_xor(s1, 16);
      int grow = mt * 2 + (lane >= 32 ? 1 : 0);
      if ((lane & 31) < 16) {
        bf16x2v o = { (__bf16)s0, (__bf16)s1 };
        *(bf16x2v*)&Sph[grow * LROW + crow] = o;
      } else {
        *(unsigned*)&Sph[(8 + grow) * LROW + crow] = 0u;  // zero pad rows
      }
    }
  }
  __syncthreads();

  // ---- phase 6: ho = relu(Sph @ WO + cO)  (M=16 tile: 8 graphs + 8 zero rows)
  {
    f32x4 acco[2];
    f32x4 zero = {0.f, 0.f, 0.f, 0.f};
    acco[0] = zero; acco[1] = zero;
    #pragma unroll
    for (int kb = 0; kb < 128; kb += 32) {
      const int ko = kb + quad * 8;
      bf16x8 fa = *(const bf16x8*)&Sph[l15 * LROW + ko];
      bf16x8 fb0 = *(const bf16x8*)&WoT[(crow) * 128 + ko];
      bf16x8 fb1 = *(const bf16x8*)&WoT[(crow + 1) * 128 + ko];
      acco[0] = MFMA16(fa, fb0, acco[0]);
      acco[1] = MFMA16(fa, fb1, acco[1]);
    }
    const f32x2 cov = *(const f32x2*)&vec[384 + crow];
    #pragma unroll
    for (int r = 0; r < 4; ++r) {
      bf16x2v o = { (__bf16)fmaxf(acco[0][r] + cov.x, 0.f),
                    (__bf16)fmaxf(acco[1][r] + cov.y, 0.f) };
      *(bf16x2v*)&hob[(quad * 4 + r) * LROW + crow] = o;
    }
  }
  __syncthreads();

  // ---- phase 7: logits = ho @ out_W2 + out_b2  (wave 0 only) UNCHANGED
  if (w == 0) {
    f32x4 accf = {0.f, 0.f, 0.f, 0.f};
    #pragma unroll
    for (int kb = 0; kb < 128; kb += 32) {
      const int ko = kb + quad * 8;
      bf16x8 fa  = *(const bf16x8*)&hob[l15 * LROW + ko];
      bf16x8 fbv = *(const bf16x8*)&Wo2T[l15 * 128 + ko];
      accf = MFMA16(fa, fbv, accf);
    }
    if (quad < 2) {
      float b2 = out_b2[l15];
      #pragma unroll
      for (int r = 0; r < 4; ++r) {
        int row = quad * 4 + r;
        out[(g0 + row) * 16 + l15] = accf[r] + b2;
      }
    }
  }
}

extern "C" void kernel_launch(void* const* d_in, const int* in_sizes, int n_in,
                              void* d_out, int out_size, void* d_ws, size_t ws_size,
                              hipStream_t stream) {
  const int*   anchors   = (const int*)d_in[0];
  const int*   n_jumps   = (const int*)d_in[1];
  const float* positions = (const float*)d_in[2];
  const int*   colors    = (const int*)d_in[3];
  const int*   markers   = (const int*)d_in[4];
  const float* pre_W1  = (const float*)d_in[5];
  const float* pre_b1  = (const float*)d_in[6];
  const float* pre_W2  = (const float*)d_in[7];
  const float* pre_b2  = (const float*)d_in[8];
  const float* msg_W1  = (const float*)d_in[9];
  const float* msg_b1  = (const float*)d_in[10];
  const float* msg_W2  = (const float*)d_in[11];
  const float* msg_b2  = (const float*)d_in[12];
  const float* post_W1 = (const float*)d_in[13];
  const float* post_b1 = (const float*)d_in[14];
  const float* post_W2 = (const float*)d_in[15];
  const float* post_b2 = (const float*)d_in[16];
  const float* out_W1  = (const float*)d_in[17];
  const float* out_b1  = (const float*)d_in[18];
  const float* out_W2  = (const float*)d_in[19];
  const float* out_b2  = (const float*)d_in[20];

  char* ws = (char*)d_ws;
  unsigned short* WabT = (unsigned short*)(ws);            // [256][128] bf16
  unsigned short* WdT  = (unsigned short*)(ws + 65536);    // [128][128]
  unsigned short* WcT  = (unsigned short*)(ws + 98304);    // [128][128]
  unsigned short* WoT  = (unsigned short*)(ws + 131072);   // [128][128]
  unsigned short* Wo2T = (unsigned short*)(ws + 163840);   // [16][128]
  float*          vecs = (float*)(ws + 167936);            // 512 f32
  unsigned short* W1pT = (unsigned short*)(ws + 169984);   // [128][64] bf16

  const int BS = in_sizes[0];

  combine_weights<<<324, 256, 0, stream>>>(
      pre_W1, pre_b1, pre_W2, msg_W1, msg_W2, post_W1, post_W2, out_W1, out_W2,
      pre_b2, msg_b1, msg_b2, post_b1, post_b2, out_b1,
      WabT, WdT, WcT, WoT, Wo2T, W1pT, vecs);

  rrn_main<<<BS / 8, 256, 0, stream>>>(
      anchors, n_jumps, positions, colors, markers,
      (const __bf16*)W1pT,
      (const __bf16*)WabT, (const __bf16*)WdT, (const __bf16*)WcT,
      (const __bf16*)WoT, (const __bf16*)Wo2T, vecs, out_b2, (float*)d_out);
}

// Round 7
// 153.978 us; speedup vs baseline: 1.1965x; 1.0004x over previous
//
#include <hip/hip_runtime.h>

#define LROW 136   // padded LDS row stride in bf16 elements (128 + 8); 272 B rows
#define FSTR 72    // feat row stride in bf16 (64 K-cols + 8 pad); 144 B rows
#define DSTR 68    // dist row stride in f32 (was 64): quads land on distinct banks

typedef __bf16 bf16x8  __attribute__((ext_vector_type(8)));
typedef __bf16 bf16x2v __attribute__((ext_vector_type(2)));
typedef float  f32x4   __attribute__((ext_vector_type(4)));
typedef float  f32x2   __attribute__((ext_vector_type(2)));

#define MFMA16(a, b, c) __builtin_amdgcn_mfma_f32_16x16x32_bf16((a), (b), (c), 0, 0, 0)

__device__ __forceinline__ float bflo(unsigned v) { return __uint_as_float(v << 16); }
__device__ __forceinline__ float bfhi(unsigned v) { return __uint_as_float(v & 0xffff0000u); }

__device__ __forceinline__ unsigned short f2bf_u16(float f) {
  unsigned u = __float_as_uint(f);
  u += 0x7fffu + ((u >> 16) & 1u);
  return (unsigned short)(u >> 16);
}

// ---------------------------------------------------------------------------
// Kernel 1: fold linear layers into combined weight matrices (bf16, [n][k]
// transposed layout) + folded bias vectors (f32) + W1pT (pre_W1 transposed,
// bias folded as feature k=42, zero-padded to K=64). UNCHANGED from R11.
// ---------------------------------------------------------------------------
__global__ void combine_weights(
    const float* __restrict__ pre_W1, const float* __restrict__ pre_b1,
    const float* __restrict__ pre_W2, const float* __restrict__ msg_W1,
    const float* __restrict__ msg_W2, const float* __restrict__ post_W1,
    const float* __restrict__ post_W2, const float* __restrict__ out_W1,
    const float* __restrict__ out_W2, const float* __restrict__ pre_b2,
    const float* __restrict__ msg_b1, const float* __restrict__ msg_b2,
    const float* __restrict__ post_b1, const float* __restrict__ post_b2,
    const float* __restrict__ out_b1,
    unsigned short* __restrict__ WabT, unsigned short* __restrict__ WdT,
    unsigned short* __restrict__ WcT, unsigned short* __restrict__ WoT,
    unsigned short* __restrict__ Wo2T, unsigned short* __restrict__ W1pT,
    float* __restrict__ vecs)
{
  __shared__ float part[256];
  const int b = blockIdx.x;
  const int t = threadIdx.x;
  if (b < 320) {
    const int p  = b >> 6;
    const int kp = b & 63;
    const int k  = kp * 2 + (t >> 7);
    const int n  = t & 127;
    const float* L; const float* R; unsigned short* O;
    if (p == 0)      { L = pre_W2;  R = msg_W1;             O = WabT; }
    else if (p == 1) { L = pre_W2;  R = msg_W1 + 128*128;   O = WabT + 128*128; }
    else if (p == 2) { L = pre_W2;  R = post_W1 + 128*128;  O = WdT; }
    else if (p == 3) { L = msg_W2;  R = post_W1;            O = WcT; }
    else             { L = post_W2; R = out_W1;             O = WoT; }
    const float* Lr = L + k * 128;
    float a0 = 0.f, a1 = 0.f, a2 = 0.f, a3 = 0.f;
    #pragma unroll 8
    for (int m = 0; m < 128; m += 4) {
      a0 = fmaf(Lr[m + 0], R[(m + 0) * 128 + n], a0);
      a1 = fmaf(Lr[m + 1], R[(m + 1) * 128 + n], a1);
      a2 = fmaf(Lr[m + 2], R[(m + 2) * 128 + n], a2);
      a3 = fmaf(Lr[m + 3], R[(m + 3) * 128 + n], a3);
    }
    O[n * 128 + k] = f2bf_u16((a0 + a1) + (a2 + a3));
  } else if (b == 320) {
    // Wo2T transpose, w1d copy, W1pT build
    for (int idx = t; idx < 16 * 128; idx += 256) {
      int o = idx >> 7, k = idx & 127;
      Wo2T[o * 128 + k] = f2bf_u16(out_W2[k * 16 + o]);
    }
    if (t < 128) vecs[t] = msg_W1[256 * 128 + t];          // w1d
    for (int idx = t; idx < 128 * 64; idx += 256) {
      int n = idx >> 6, k = idx & 63;
      float v = (k < 42) ? pre_W1[k * 128 + n] : (k == 42 ? pre_b1[n] : 0.f);
      W1pT[n * 64 + k] = f2bf_u16(v);
    }
  } else {
    const int n = t & 127;
    const int h = t >> 7;
    float s = 0.f;
    if (b == 321) {            // cAB = pre_b2@(W1a+W1b) + msg_b1
      #pragma unroll 8
      for (int m = h * 64; m < h * 64 + 64; ++m)
        s = fmaf(pre_b2[m], msg_W1[m * 128 + n] + msg_W1[(128 + m) * 128 + n], s);
    } else if (b == 322) {     // cP = 7*msg_b2@P1a + pre_b2@P1b + post_b1
      #pragma unroll 8
      for (int m = h * 64; m < h * 64 + 64; ++m) {
        s = fmaf(7.f * msg_b2[m], post_W1[m * 128 + n], s);
        s = fmaf(pre_b2[m], post_W1[(128 + m) * 128 + n], s);
      }
    } else {                   // cO = 8*post_b2@out_W1 + out_b1
      #pragma unroll 8
      for (int m = h * 64; m < h * 64 + 64; ++m)
        s = fmaf(8.f * post_b2[m], out_W1[m * 128 + n], s);
    }
    part[t] = s;
    __syncthreads();
    if (t < 128) {
      float r = part[t] + part[t + 128];
      if (b == 321)      vecs[128 + t] = r + msg_b1[t];
      else if (b == 322) vecs[256 + t] = r + post_b1[t];
      else               vecs[384 + t] = r + out_b1[t];
    }
  }
}

// ---------------------------------------------------------------------------
// Kernel 2: fully fused RRN. R19 = EXACT R12 (56.4us known-good: M=64,
// 4 waves, 2048 blocks, f32 scalar phase 4, launch_bounds(256,4)) with ONLY
// the two ADDRESS-LEVEL fixes R18 validated (R18's f16 datatype change
// caused scratch, +5MB writes -- dropped):
// (1) phase-4 ROW-ROTATION m=4*(quad&1): slot (i,j) -> actual rows
//     (i^m, j^m). Quads {1,3} land +16 banks from {0,2} -> Ab/Bb phase-4
//     traffic goes 4-way -> 2-way (free). Validated: conflicts 4.0M->2.0M.
// (2) dist stride 64 -> 68 dwords: quad broadcast-reads land +8 banks apart
//     (was all-same-bank, 4-way on every dist read).
// Math, arrays, liveness bit-identical to R12 -- only index arithmetic.
// ---------------------------------------------------------------------------
__global__ void __launch_bounds__(256, 4) rrn_main(
    const int* __restrict__ anchors, const int* __restrict__ n_jumps,
    const float* __restrict__ positions, const int* __restrict__ colors,
    const int* __restrict__ markers,
    const __bf16* __restrict__ W1pT,
    const __bf16* __restrict__ WabT, const __bf16* __restrict__ WdT,
    const __bf16* __restrict__ WcT, const __bf16* __restrict__ WoT,
    const __bf16* __restrict__ Wo2T, const float* __restrict__ vecs,
    const float* __restrict__ out_b2, float* __restrict__ out)
{
  __shared__ __align__(16) char smem[39040];
  // X [0,17408): phases 0-1: featL bf16[64][FSTR]. Phase 2+: Ab (A, then S).
  // Y [17408,34816): h1 (phases 1-2); Bb after h1-drain; Sph @17408 /
  //   hob @21760 (phases 5+).  dist f32[8*DSTR] @34816; vec f32[512] @36992.
  __bf16* featL = (__bf16*)(smem);
  __bf16* Ab    = (__bf16*)(smem);
  __bf16* h1    = (__bf16*)(smem + 17408);
  __bf16* Bb    = (__bf16*)(smem + 17408);
  __bf16* Sph   = (__bf16*)(smem + 17408);
  __bf16* hob   = (__bf16*)(smem + 21760);
  float*  dist  = (float*)(smem + 34816);
  float*  vec   = (float*)(smem + 36992);

  const int tid  = threadIdx.x;
  const int lane = tid & 63;
  const int w    = tid >> 6;      // wave 0..3
  const int l15  = lane & 15;
  const int quad = lane >> 4;
  const int colw = w * 32;        // this wave's 32-col slice
  const int crow = colw + 2 * l15; // paired-col base: lane owns cols crow, crow+1
  const int g0   = blockIdx.x * 8;
  const int n0   = blockIdx.x * 64;

  // ---- phase 0: build feature rows (thread-private: no race), dist, vec
  if (tid < 64) {
    uint4* rp = (uint4*)&featL[tid * FSTR];   // 144 B row, 16B-aligned
    uint4 z4 = {0u, 0u, 0u, 0u};
    #pragma unroll
    for (int i = 0; i < 9; ++i) rp[i] = z4;
    int g = tid >> 3;
    float px = positions[(n0 + tid) * 2], py = positions[(n0 + tid) * 2 + 1];
    int c  = colors[n0 + tid], mk = markers[n0 + tid] - 8;
    int a  = anchors[g0 + g],  nj = n_jumps[g0 + g];
    __bf16* row = &featL[tid * FSTR];
    row[0] = (__bf16)px; row[1] = (__bf16)py;
    const __bf16 one = (__bf16)1.f;
    row[2 + c] = one; row[10 + mk] = one;
    row[18 + a] = one; row[34 + nj] = one;
    row[42] = one;                              // bias-as-feature
  }
  for (int i = tid; i < 512; i += 256) {
    int g = i >> 6, ii = (i >> 3) & 7, jj = i & 7;
    const float* pa = positions + (n0 + g * 8 + ii) * 2;
    const float* pb = positions + (n0 + g * 8 + jj) * 2;
    float dx = pa[0] - pb[0], dy = pa[1] - pb[1];
    dist[g * DSTR + (i & 63)] = sqrtf(dx * dx + dy * dy);
  }
  for (int i = tid; i < 512; i += 256) vec[i] = vecs[i];
  __syncthreads();

  // ---- phase 1: h1 = relu(featL @ W1pT) via MFMA (M=64, N=128, K=64 padded).
  //      B-frag lanes load W1pT rows crow, crow+1 -> adjacent output cols.
  {
    f32x4 acch[4][2];
    f32x4 zero = {0.f, 0.f, 0.f, 0.f};
    #pragma unroll
    for (int mt = 0; mt < 4; ++mt) { acch[mt][0] = zero; acch[mt][1] = zero; }
    #pragma unroll
    for (int kb = 0; kb < 64; kb += 32) {
      const int ko = kb + quad * 8;
      bf16x8 fa[4], fb[2];
      #pragma unroll
      for (int mt = 0; mt < 4; ++mt)
        fa[mt] = *(const bf16x8*)&featL[(mt * 16 + l15) * FSTR + ko];
      fb[0] = *(const bf16x8*)&W1pT[(crow) * 64 + ko];
      fb[1] = *(const bf16x8*)&W1pT[(crow + 1) * 64 + ko];
      #pragma unroll
      for (int mt = 0; mt < 4; ++mt) {
        acch[mt][0] = MFMA16(fa[mt], fb[0], acch[mt][0]);
        acch[mt][1] = MFMA16(fa[mt], fb[1], acch[mt][1]);
      }
    }
    #pragma unroll
    for (int mt = 0; mt < 4; ++mt)
      #pragma unroll
      for (int r = 0; r < 4; ++r) {
        bf16x2v o = { (__bf16)fmaxf(acch[mt][0][r], 0.f),
                      (__bf16)fmaxf(acch[mt][1][r], 0.f) };
        *(bf16x2v*)&h1[(mt * 16 + quad * 4 + r) * LROW + crow] = o;
      }
  }
  __syncthreads();   // featL reads done + h1 visible

  // ---- phase 2 pass 1: [A|B] cols crow,crow+1 (x A,B halves) = h1 @ WabT
  f32x4 acc1[4][4];   // nt 0,1 -> A cols crow,crow+1; nt 2,3 -> B cols crow,crow+1
  {
    f32x4 zero = {0.f, 0.f, 0.f, 0.f};
    #pragma unroll
    for (int mt = 0; mt < 4; ++mt)
      #pragma unroll
      for (int nt = 0; nt < 4; ++nt) acc1[mt][nt] = zero;
  }
  #pragma unroll
  for (int kb = 0; kb < 128; kb += 32) {
    const int ko = kb + quad * 8;
    bf16x8 fa[4], fb[4];
    #pragma unroll
    for (int mt = 0; mt < 4; ++mt)
      fa[mt] = *(const bf16x8*)&h1[(mt * 16 + l15) * LROW + ko];
    fb[0] = *(const bf16x8*)&WabT[(crow) * 128 + ko];
    fb[1] = *(const bf16x8*)&WabT[(crow + 1) * 128 + ko];
    fb[2] = *(const bf16x8*)&WabT[(128 + crow) * 128 + ko];
    fb[3] = *(const bf16x8*)&WabT[(128 + crow + 1) * 128 + ko];
    #pragma unroll
    for (int mt = 0; mt < 4; ++mt)
      #pragma unroll
      for (int nt = 0; nt < 4; ++nt)
        acc1[mt][nt] = MFMA16(fa[mt], fb[nt], acc1[mt][nt]);
  }
  // write back A now (featL dead since post-phase-1 barrier); own cols only.
  #pragma unroll
  for (int mt = 0; mt < 4; ++mt)
    #pragma unroll
    for (int r = 0; r < 4; ++r) {
      bf16x2v o = { (__bf16)acc1[mt][0][r], (__bf16)acc1[mt][1][r] };
      *(bf16x2v*)&Ab[(mt * 16 + quad * 4 + r) * LROW + crow] = o;
    }

  // ---- phase 2 pass 2: D cols crow,crow+1 = h1 @ WdT (8 accs, live to ph5)
  f32x4 accD[4][2];
  {
    f32x4 zero = {0.f, 0.f, 0.f, 0.f};
    #pragma unroll
    for (int mt = 0; mt < 4; ++mt) { accD[mt][0] = zero; accD[mt][1] = zero; }
  }
  #pragma unroll
  for (int kb = 0; kb < 128; kb += 32) {
    const int ko = kb + quad * 8;
    bf16x8 fa[4], fd[2];
    #pragma unroll
    for (int mt = 0; mt < 4; ++mt)
      fa[mt] = *(const bf16x8*)&h1[(mt * 16 + l15) * LROW + ko];
    fd[0] = *(const bf16x8*)&WdT[(crow) * 128 + ko];
    fd[1] = *(const bf16x8*)&WdT[(crow + 1) * 128 + ko];
    #pragma unroll
    for (int mt = 0; mt < 4; ++mt) {
      accD[mt][0] = MFMA16(fa[mt], fd[0], accD[mt][0]);
      accD[mt][1] = MFMA16(fa[mt], fd[1], accD[mt][1]);
    }
  }
  __syncthreads();   // h1 drain: all waves done reading Y before B overwrites it
  // write back B over the dead h1 region; own cols only -> NO barrier after.
  #pragma unroll
  for (int mt = 0; mt < 4; ++mt)
    #pragma unroll
    for (int r = 0; r < 4; ++r) {
      bf16x2v o = { (__bf16)acc1[mt][2][r], (__bf16)acc1[mt][3][r] };
      *(bf16x2v*)&Bb[(mt * 16 + quad * 4 + r) * LROW + crow] = o;
    }

  // ---- phase 4: edges, own-column mapping (no barrier since B write):
  //      wave w covers its cols colw..+31; quad -> graph pair; lane l15 ->
  //      adjacent col pair. ROW-ROTATION m=4*(quad&1): slot (i,j) -> actual
  //      rows (i^m, j^m); dist indexed by actual rows; diagonal skip j==i is
  //      slot==slot (compile-time). S[i]=sum_{j!=i} relu(A[i]+B[j]+d*w1d+cAB),
  //      written in place over A (same wave-owned cols). f32 math = R12.
  {
    const int c0 = colw + ((l15 & 8) << 1) + 2 * (l15 & 7);  // adjacent pair c0,c0+1
    const int m  = (quad & 1) << 2;                          // row rotation
    const f32x2 wv = { vec[c0], vec[c0 + 1] };
    const f32x2 cv = { vec[128 + c0], vec[128 + c0 + 1] };
    const f32x2 z2 = {0.f, 0.f};
    #pragma unroll
    for (int gi = 0; gi < 2; ++gi) {
      const int g = 2 * quad + gi;
      f32x2 Bj[8];   // slot-indexed: Bj[j] = B row (j^m)
      #pragma unroll
      for (int j = 0; j < 8; ++j) {
        unsigned vb = *(const unsigned*)&Bb[(g * 8 + (j ^ m)) * LROW + c0];
        Bj[j].x = bflo(vb); Bj[j].y = bfhi(vb);
      }
      #pragma unroll
      for (int i = 0; i < 8; ++i) {
        const int ia = i ^ m;
        unsigned va = *(const unsigned*)&Ab[(g * 8 + ia) * LROW + c0];
        f32x2 a = {bflo(va) + cv.x, bfhi(va) + cv.y};
        f32x2 s = z2;
        #pragma unroll
        for (int j = 0; j < 8; ++j) {
          if (j == i) continue;   // slot diagonal == actual diagonal
          float d = dist[g * DSTR + ia * 8 + (j ^ m)];
          f32x2 d2 = {d, d};
          f32x2 t = __builtin_elementwise_fma(d2, wv, Bj[j]) + a;
          s += __builtin_elementwise_max(t, z2);
        }
        unsigned o = (unsigned)f2bf_u16(s.x) | ((unsigned)f2bf_u16(s.y) << 16);
        *(unsigned*)&Ab[(g * 8 + ia) * LROW + c0] = o;   // in-place S
      }
    }
  }
  __syncthreads();   // S visible to all waves

  // ---- phase 5: ph = relu(S@Wc + D + cP); per-graph sum -> Sph (pad rows
  //      zeroed). fc rows crow,crow+1 match accD's col assignment.
  {
    const __bf16* Sb = Ab;
    #pragma unroll
    for (int kb = 0; kb < 128; kb += 32) {
      const int ko = kb + quad * 8;
      bf16x8 fa[4], fc[2];
      #pragma unroll
      for (int mt = 0; mt < 4; ++mt)
        fa[mt] = *(const bf16x8*)&Sb[(mt * 16 + l15) * LROW + ko];
      fc[0] = *(const bf16x8*)&WcT[(crow) * 128 + ko];
      fc[1] = *(const bf16x8*)&WcT[(crow + 1) * 128 + ko];
      #pragma unroll
      for (int mt = 0; mt < 4; ++mt) {
        accD[mt][0] = MFMA16(fa[mt], fc[0], accD[mt][0]);
        accD[mt][1] = MFMA16(fa[mt], fc[1], accD[mt][1]);
      }
    }
    const f32x2 cpv = *(const f32x2*)&vec[256 + crow];
    #pragma unroll
    for (int mt = 0; mt < 4; ++mt) {
      f32x4 a0 = accD[mt][0];
      f32x4 a1 = accD[mt][1];
      float s0 = fmaxf(a0[0] + cpv.x, 0.f) + fmaxf(a0[1] + cpv.x, 0.f)
               + fmaxf(a0[2] + cpv.x, 0.f) + fmaxf(a0[3] + cpv.x, 0.f);
      float s1 = fmaxf(a1[0] + cpv.y, 0.f) + fmaxf(a1[1] + cpv.y, 0.f)
               + fmaxf(a1[2] + cpv.y, 0.f) + fmaxf(a1[3] + cpv.y, 0.f);
      s0 += __shfl_xor(s0, 16);
      s1 += __shfl_xor(s1, 16);
      int grow = mt * 2 + (lane >= 32 ? 1 : 0);
      if ((lane & 31) < 16) {
        bf16x2v o = { (__bf16)s0, (__bf16)s1 };
        *(bf16x2v*)&Sph[grow * LROW + crow] = o;
      } else {
        *(unsigned*)&Sph[(8 + grow) * LROW + crow] = 0u;  // zero pad rows
      }
    }
  }
  __syncthreads();

  // ---- phase 6: ho = relu(Sph @ WO + cO)  (M=16 tile: 8 graphs + 8 zero rows)
  {
    f32x4 acco[2];
    f32x4 zero = {0.f, 0.f, 0.f, 0.f};
    acco[0] = zero; acco[1] = zero;
    #pragma unroll
    for (int kb = 0; kb < 128; kb += 32) {
      const int ko = kb + quad * 8;
      bf16x8 fa = *(const bf16x8*)&Sph[l15 * LROW + ko];
      bf16x8 fb0 = *(const bf16x8*)&WoT[(crow) * 128 + ko];
      bf16x8 fb1 = *(const bf16x8*)&WoT[(crow + 1) * 128 + ko];
      acco[0] = MFMA16(fa, fb0, acco[0]);
      acco[1] = MFMA16(fa, fb1, acco[1]);
    }
    const f32x2 cov = *(const f32x2*)&vec[384 + crow];
    #pragma unroll
    for (int r = 0; r < 4; ++r) {
      bf16x2v o = { (__bf16)fmaxf(acco[0][r] + cov.x, 0.f),
                    (__bf16)fmaxf(acco[1][r] + cov.y, 0.f) };
      *(bf16x2v*)&hob[(quad * 4 + r) * LROW + crow] = o;
    }
  }
  __syncthreads();

  // ---- phase 7: logits = ho @ out_W2 + out_b2  (wave 0 only) UNCHANGED
  if (w == 0) {
    f32x4 accf = {0.f, 0.f, 0.f, 0.f};
    #pragma unroll
    for (int kb = 0; kb < 128; kb += 32) {
      const int ko = kb + quad * 8;
      bf16x8 fa  = *(const bf16x8*)&hob[l15 * LROW + ko];
      bf16x8 fbv = *(const bf16x8*)&Wo2T[l15 * 128 + ko];
      accf = MFMA16(fa, fbv, accf);
    }
    if (quad < 2) {
      float b2 = out_b2[l15];
      #pragma unroll
      for (int r = 0; r < 4; ++r) {
        int row = quad * 4 + r;
        out[(g0 + row) * 16 + l15] = accf[r] + b2;
      }
    }
  }
}

extern "C" void kernel_launch(void* const* d_in, const int* in_sizes, int n_in,
                              void* d_out, int out_size, void* d_ws, size_t ws_size,
                              hipStream_t stream) {
  const int*   anchors   = (const int*)d_in[0];
  const int*   n_jumps   = (const int*)d_in[1];
  const float* positions = (const float*)d_in[2];
  const int*   colors    = (const int*)d_in[3];
  const int*   markers   = (const int*)d_in[4];
  const float* pre_W1  = (const float*)d_in[5];
  const float* pre_b1  = (const float*)d_in[6];
  const float* pre_W2  = (const float*)d_in[7];
  const float* pre_b2  = (const float*)d_in[8];
  const float* msg_W1  = (const float*)d_in[9];
  const float* msg_b1  = (const float*)d_in[10];
  const float* msg_W2  = (const float*)d_in[11];
  const float* msg_b2  = (const float*)d_in[12];
  const float* post_W1 = (const float*)d_in[13];
  const float* post_b1 = (const float*)d_in[14];
  const float* post_W2 = (const float*)d_in[15];
  const float* post_b2 = (const float*)d_in[16];
  const float* out_W1  = (const float*)d_in[17];
  const float* out_b1  = (const float*)d_in[18];
  const float* out_W2  = (const float*)d_in[19];
  const float* out_b2  = (const float*)d_in[20];

  char* ws = (char*)d_ws;
  unsigned short* WabT = (unsigned short*)(ws);            // [256][128] bf16
  unsigned short* WdT  = (unsigned short*)(ws + 65536);    // [128][128]
  unsigned short* WcT  = (unsigned short*)(ws + 98304);    // [128][128]
  unsigned short* WoT  = (unsigned short*)(ws + 131072);   // [128][128]
  unsigned short* Wo2T = (unsigned short*)(ws + 163840);   // [16][128]
  float*          vecs = (float*)(ws + 167936);            // 512 f32
  unsigned short* W1pT = (unsigned short*)(ws + 169984);   // [128][64] bf16

  const int BS = in_sizes[0];

  combine_weights<<<324, 256, 0, stream>>>(
      pre_W1, pre_b1, pre_W2, msg_W1, msg_W2, post_W1, post_W2, out_W1, out_W2,
      pre_b2, msg_b1, msg_b2, post_b1, post_b2, out_b1,
      WabT, WdT, WcT, WoT, Wo2T, W1pT, vecs);

  rrn_main<<<BS / 8, 256, 0, stream>>>(
      anchors, n_jumps, positions, colors, markers,
      (const __bf16*)W1pT,
      (const __bf16*)WabT, (const __bf16*)WdT, (const __bf16*)WcT,
      (const __bf16*)WoT, (const __bf16*)Wo2T, vecs, out_b2, (float*)d_out);
}

// Round 8
// 152.135 us; speedup vs baseline: 1.2110x; 1.0121x over previous
//
#include <hip/hip_runtime.h>

#define LROW 136   // padded LDS row stride in bf16 elements (128 + 8); 272 B rows
#define FSTR 72    // feat row stride in bf16 (64 K-cols + 8 pad); 144 B rows

typedef __bf16 bf16x8  __attribute__((ext_vector_type(8)));
typedef __bf16 bf16x2v __attribute__((ext_vector_type(2)));
typedef float  f32x4   __attribute__((ext_vector_type(4)));
typedef float  f32x2   __attribute__((ext_vector_type(2)));

#define MFMA16(a, b, c) __builtin_amdgcn_mfma_f32_16x16x32_bf16((a), (b), (c), 0, 0, 0)

__device__ __forceinline__ float bflo(unsigned v) { return __uint_as_float(v << 16); }
__device__ __forceinline__ float bfhi(unsigned v) { return __uint_as_float(v & 0xffff0000u); }

__device__ __forceinline__ unsigned short f2bf_u16(float f) {
  unsigned u = __float_as_uint(f);
  u += 0x7fffu + ((u >> 16) & 1u);
  return (unsigned short)(u >> 16);
}

// ---------------------------------------------------------------------------
// Kernel 1: fold linear layers into combined weight matrices (bf16, [n][k]
// transposed layout) + folded bias vectors (f32) + W1pT (pre_W1 transposed,
// bias folded as feature k=42, zero-padded to K=64). UNCHANGED from R11.
// ---------------------------------------------------------------------------
__global__ void combine_weights(
    const float* __restrict__ pre_W1, const float* __restrict__ pre_b1,
    const float* __restrict__ pre_W2, const float* __restrict__ msg_W1,
    const float* __restrict__ msg_W2, const float* __restrict__ post_W1,
    const float* __restrict__ post_W2, const float* __restrict__ out_W1,
    const float* __restrict__ out_W2, const float* __restrict__ pre_b2,
    const float* __restrict__ msg_b1, const float* __restrict__ msg_b2,
    const float* __restrict__ post_b1, const float* __restrict__ post_b2,
    const float* __restrict__ out_b1,
    unsigned short* __restrict__ WabT, unsigned short* __restrict__ WdT,
    unsigned short* __restrict__ WcT, unsigned short* __restrict__ WoT,
    unsigned short* __restrict__ Wo2T, unsigned short* __restrict__ W1pT,
    float* __restrict__ vecs)
{
  __shared__ float part[256];
  const int b = blockIdx.x;
  const int t = threadIdx.x;
  if (b < 320) {
    const int p  = b >> 6;
    const int kp = b & 63;
    const int k  = kp * 2 + (t >> 7);
    const int n  = t & 127;
    const float* L; const float* R; unsigned short* O;
    if (p == 0)      { L = pre_W2;  R = msg_W1;             O = WabT; }
    else if (p == 1) { L = pre_W2;  R = msg_W1 + 128*128;   O = WabT + 128*128; }
    else if (p == 2) { L = pre_W2;  R = post_W1 + 128*128;  O = WdT; }
    else if (p == 3) { L = msg_W2;  R = post_W1;            O = WcT; }
    else             { L = post_W2; R = out_W1;             O = WoT; }
    const float* Lr = L + k * 128;
    float a0 = 0.f, a1 = 0.f, a2 = 0.f, a3 = 0.f;
    #pragma unroll 8
    for (int m = 0; m < 128; m += 4) {
      a0 = fmaf(Lr[m + 0], R[(m + 0) * 128 + n], a0);
      a1 = fmaf(Lr[m + 1], R[(m + 1) * 128 + n], a1);
      a2 = fmaf(Lr[m + 2], R[(m + 2) * 128 + n], a2);
      a3 = fmaf(Lr[m + 3], R[(m + 3) * 128 + n], a3);
    }
    O[n * 128 + k] = f2bf_u16((a0 + a1) + (a2 + a3));
  } else if (b == 320) {
    // Wo2T transpose, w1d copy, W1pT build
    for (int idx = t; idx < 16 * 128; idx += 256) {
      int o = idx >> 7, k = idx & 127;
      Wo2T[o * 128 + k] = f2bf_u16(out_W2[k * 16 + o]);
    }
    if (t < 128) vecs[t] = msg_W1[256 * 128 + t];          // w1d
    for (int idx = t; idx < 128 * 64; idx += 256) {
      int n = idx >> 6, k = idx & 63;
      float v = (k < 42) ? pre_W1[k * 128 + n] : (k == 42 ? pre_b1[n] : 0.f);
      W1pT[n * 64 + k] = f2bf_u16(v);
    }
  } else {
    const int n = t & 127;
    const int h = t >> 7;
    float s = 0.f;
    if (b == 321) {            // cAB = pre_b2@(W1a+W1b) + msg_b1
      #pragma unroll 8
      for (int m = h * 64; m < h * 64 + 64; ++m)
        s = fmaf(pre_b2[m], msg_W1[m * 128 + n] + msg_W1[(128 + m) * 128 + n], s);
    } else if (b == 322) {     // cP = 7*msg_b2@P1a + pre_b2@P1b + post_b1
      #pragma unroll 8
      for (int m = h * 64; m < h * 64 + 64; ++m) {
        s = fmaf(7.f * msg_b2[m], post_W1[m * 128 + n], s);
        s = fmaf(pre_b2[m], post_W1[(128 + m) * 128 + n], s);
      }
    } else {                   // cO = 8*post_b2@out_W1 + out_b1
      #pragma unroll 8
      for (int m = h * 64; m < h * 64 + 64; ++m)
        s = fmaf(8.f * post_b2[m], out_W1[m * 128 + n], s);
    }
    part[t] = s;
    __syncthreads();
    if (t < 128) {
      float r = part[t] + part[t + 128];
      if (b == 321)      vecs[128 + t] = r + msg_b1[t];
      else if (b == 322) vecs[256 + t] = r + post_b1[t];
      else               vecs[384 + t] = r + out_b1[t];
    }
  }
}

// ---------------------------------------------------------------------------
// Kernel 2: fully fused RRN. R20 = EXACT R12 RESTORED (56.4us, twice
// verified; best known). Session findings R13-R19, recorded for posterity:
// - R13 (M=32, 2x grid): -70%. Weight-fragment amortization + chip-wide
//   phase-latency traversals dominate; never shrink the M-tile.
// - R14 (acc-split @ M=64): spills (+6MB WRITE). R15 (8-wave row-split):
//   occupancy 56% but -54%. Occupancy is NOT the binding resource.
// - R16 (register-resident ph4): spills. R18 (f16 ph4): spills.
// - R19 (pure XOR-rotation + dist stride): conflicts 4.0M->2.0M with ZERO
//   time gain (+4us from ~2.5 dwords/lane scratch) => phase-4 bank
//   conflicts are fully latency-hidden, AND this codegen sits exactly on
//   the unified VGPR+AGPR cliff (64+96=160/wave = 3 waves/SIMD): ANY extra
//   register tips it into scratch. Do not perturb phase 4, the launch
//   bounds, or register liveness. The kernel is latency-bound on its
//   6-barrier phase chain at 3 blocks/CU; all pipes <=30% busy.
// ---------------------------------------------------------------------------
__global__ void __launch_bounds__(256, 4) rrn_main(
    const int* __restrict__ anchors, const int* __restrict__ n_jumps,
    const float* __restrict__ positions, const int* __restrict__ colors,
    const int* __restrict__ markers,
    const __bf16* __restrict__ W1pT,
    const __bf16* __restrict__ WabT, const __bf16* __restrict__ WdT,
    const __bf16* __restrict__ WcT, const __bf16* __restrict__ WoT,
    const __bf16* __restrict__ Wo2T, const float* __restrict__ vecs,
    const float* __restrict__ out_b2, float* __restrict__ out)
{
  __shared__ __align__(16) char smem[38912];
  // X [0,17408): phases 0-1: featL bf16[64][FSTR]. Phase 2+: Ab (A, then S).
  // Y [17408,34816): h1 (phases 1-2); Bb after h1-drain; Sph @17408 /
  //   hob @21760 (phases 5+).  dist f32[512] @34816; vec f32[512] @36864.
  __bf16* featL = (__bf16*)(smem);
  __bf16* Ab    = (__bf16*)(smem);
  __bf16* h1    = (__bf16*)(smem + 17408);
  __bf16* Bb    = (__bf16*)(smem + 17408);
  __bf16* Sph   = (__bf16*)(smem + 17408);
  __bf16* hob   = (__bf16*)(smem + 21760);
  float*  dist  = (float*)(smem + 34816);
  float*  vec   = (float*)(smem + 36864);

  const int tid  = threadIdx.x;
  const int lane = tid & 63;
  const int w    = tid >> 6;      // wave 0..3
  const int l15  = lane & 15;
  const int quad = lane >> 4;
  const int colw = w * 32;        // this wave's 32-col slice
  const int crow = colw + 2 * l15; // paired-col base: lane owns cols crow, crow+1
  const int g0   = blockIdx.x * 8;
  const int n0   = blockIdx.x * 64;

  // ---- phase 0: build feature rows (thread-private: no race), dist, vec
  if (tid < 64) {
    uint4* rp = (uint4*)&featL[tid * FSTR];   // 144 B row, 16B-aligned
    uint4 z4 = {0u, 0u, 0u, 0u};
    #pragma unroll
    for (int i = 0; i < 9; ++i) rp[i] = z4;
    int g = tid >> 3;
    float px = positions[(n0 + tid) * 2], py = positions[(n0 + tid) * 2 + 1];
    int c  = colors[n0 + tid], mk = markers[n0 + tid] - 8;
    int a  = anchors[g0 + g],  nj = n_jumps[g0 + g];
    __bf16* row = &featL[tid * FSTR];
    row[0] = (__bf16)px; row[1] = (__bf16)py;
    const __bf16 one = (__bf16)1.f;
    row[2 + c] = one; row[10 + mk] = one;
    row[18 + a] = one; row[34 + nj] = one;
    row[42] = one;                              // bias-as-feature
  }
  for (int i = tid; i < 512; i += 256) {
    int g = i >> 6, ii = (i >> 3) & 7, jj = i & 7;
    const float* pa = positions + (n0 + g * 8 + ii) * 2;
    const float* pb = positions + (n0 + g * 8 + jj) * 2;
    float dx = pa[0] - pb[0], dy = pa[1] - pb[1];
    dist[i] = sqrtf(dx * dx + dy * dy);
  }
  for (int i = tid; i < 512; i += 256) vec[i] = vecs[i];
  __syncthreads();

  // ---- phase 1: h1 = relu(featL @ W1pT) via MFMA (M=64, N=128, K=64 padded).
  //      B-frag lanes load W1pT rows crow, crow+1 -> adjacent output cols.
  {
    f32x4 acch[4][2];
    f32x4 zero = {0.f, 0.f, 0.f, 0.f};
    #pragma unroll
    for (int mt = 0; mt < 4; ++mt) { acch[mt][0] = zero; acch[mt][1] = zero; }
    #pragma unroll
    for (int kb = 0; kb < 64; kb += 32) {
      const int ko = kb + quad * 8;
      bf16x8 fa[4], fb[2];
      #pragma unroll
      for (int mt = 0; mt < 4; ++mt)
        fa[mt] = *(const bf16x8*)&featL[(mt * 16 + l15) * FSTR + ko];
      fb[0] = *(const bf16x8*)&W1pT[(crow) * 64 + ko];
      fb[1] = *(const bf16x8*)&W1pT[(crow + 1) * 64 + ko];
      #pragma unroll
      for (int mt = 0; mt < 4; ++mt) {
        acch[mt][0] = MFMA16(fa[mt], fb[0], acch[mt][0]);
        acch[mt][1] = MFMA16(fa[mt], fb[1], acch[mt][1]);
      }
    }
    #pragma unroll
    for (int mt = 0; mt < 4; ++mt)
      #pragma unroll
      for (int r = 0; r < 4; ++r) {
        bf16x2v o = { (__bf16)fmaxf(acch[mt][0][r], 0.f),
                      (__bf16)fmaxf(acch[mt][1][r], 0.f) };
        *(bf16x2v*)&h1[(mt * 16 + quad * 4 + r) * LROW + crow] = o;
      }
  }
  __syncthreads();   // featL reads done + h1 visible

  // ---- phase 2 pass 1: [A|B] cols crow,crow+1 (x A,B halves) = h1 @ WabT
  f32x4 acc1[4][4];   // nt 0,1 -> A cols crow,crow+1; nt 2,3 -> B cols crow,crow+1
  {
    f32x4 zero = {0.f, 0.f, 0.f, 0.f};
    #pragma unroll
    for (int mt = 0; mt < 4; ++mt)
      #pragma unroll
      for (int nt = 0; nt < 4; ++nt) acc1[mt][nt] = zero;
  }
  #pragma unroll
  for (int kb = 0; kb < 128; kb += 32) {
    const int ko = kb + quad * 8;
    bf16x8 fa[4], fb[4];
    #pragma unroll
    for (int mt = 0; mt < 4; ++mt)
      fa[mt] = *(const bf16x8*)&h1[(mt * 16 + l15) * LROW + ko];
    fb[0] = *(const bf16x8*)&WabT[(crow) * 128 + ko];
    fb[1] = *(const bf16x8*)&WabT[(crow + 1) * 128 + ko];
    fb[2] = *(const bf16x8*)&WabT[(128 + crow) * 128 + ko];
    fb[3] = *(const bf16x8*)&WabT[(128 + crow + 1) * 128 + ko];
    #pragma unroll
    for (int mt = 0; mt < 4; ++mt)
      #pragma unroll
      for (int nt = 0; nt < 4; ++nt)
        acc1[mt][nt] = MFMA16(fa[mt], fb[nt], acc1[mt][nt]);
  }
  // write back A now (featL dead since post-phase-1 barrier); own cols only.
  #pragma unroll
  for (int mt = 0; mt < 4; ++mt)
    #pragma unroll
    for (int r = 0; r < 4; ++r) {
      bf16x2v o = { (__bf16)acc1[mt][0][r], (__bf16)acc1[mt][1][r] };
      *(bf16x2v*)&Ab[(mt * 16 + quad * 4 + r) * LROW + crow] = o;
    }

  // ---- phase 2 pass 2: D cols crow,crow+1 = h1 @ WdT (8 accs, live to ph5)
  f32x4 accD[4][2];
  {
    f32x4 zero = {0.f, 0.f, 0.f, 0.f};
    #pragma unroll
    for (int mt = 0; mt < 4; ++mt) { accD[mt][0] = zero; accD[mt][1] = zero; }
  }
  #pragma unroll
  for (int kb = 0; kb < 128; kb += 32) {
    const int ko = kb + quad * 8;
    bf16x8 fa[4], fd[2];
    #pragma unroll
    for (int mt = 0; mt < 4; ++mt)
      fa[mt] = *(const bf16x8*)&h1[(mt * 16 + l15) * LROW + ko];
    fd[0] = *(const bf16x8*)&WdT[(crow) * 128 + ko];
    fd[1] = *(const bf16x8*)&WdT[(crow + 1) * 128 + ko];
    #pragma unroll
    for (int mt = 0; mt < 4; ++mt) {
      accD[mt][0] = MFMA16(fa[mt], fd[0], accD[mt][0]);
      accD[mt][1] = MFMA16(fa[mt], fd[1], accD[mt][1]);
    }
  }
  __syncthreads();   // h1 drain: all waves done reading Y before B overwrites it
  // write back B over the dead h1 region; own cols only -> NO barrier after.
  #pragma unroll
  for (int mt = 0; mt < 4; ++mt)
    #pragma unroll
    for (int r = 0; r < 4; ++r) {
      bf16x2v o = { (__bf16)acc1[mt][2][r], (__bf16)acc1[mt][3][r] };
      *(bf16x2v*)&Bb[(mt * 16 + quad * 4 + r) * LROW + crow] = o;
    }

  // ---- phase 4: edges, OWN-COLUMN mapping (no barrier since B write):
  //      wave w covers its cols colw..+31; quad -> graph pair; lane l15 ->
  //      adjacent col pair. S[i] = sum_{j!=i} relu(A[i]+B[j]+d_ij*w1d+cAB),
  //      written in place over A (same wave-owned cols). UNCHANGED from R12.
  {
    const int c0 = colw + ((l15 & 8) << 1) + 2 * (l15 & 7);  // adjacent pair c0,c0+1
    const f32x2 wv = { vec[c0], vec[c0 + 1] };
    const f32x2 cv = { vec[128 + c0], vec[128 + c0 + 1] };
    const f32x2 z2 = {0.f, 0.f};
    #pragma unroll
    for (int gi = 0; gi < 2; ++gi) {
      const int g = 2 * quad + gi;
      f32x2 Bj[8];
      #pragma unroll
      for (int j = 0; j < 8; ++j) {
        unsigned vb = *(const unsigned*)&Bb[(g * 8 + j) * LROW + c0];
        Bj[j].x = bflo(vb); Bj[j].y = bfhi(vb);
      }
      #pragma unroll
      for (int i = 0; i < 8; ++i) {
        unsigned va = *(const unsigned*)&Ab[(g * 8 + i) * LROW + c0];
        f32x2 a = {bflo(va) + cv.x, bfhi(va) + cv.y};
        f32x2 s = z2;
        #pragma unroll
        for (int j = 0; j < 8; ++j) {
          if (j == i) continue;
          float d = dist[g * 64 + i * 8 + j];
          f32x2 d2 = {d, d};
          f32x2 t = __builtin_elementwise_fma(d2, wv, Bj[j]) + a;
          s += __builtin_elementwise_max(t, z2);
        }
        unsigned o = (unsigned)f2bf_u16(s.x) | ((unsigned)f2bf_u16(s.y) << 16);
        *(unsigned*)&Ab[(g * 8 + i) * LROW + c0] = o;   // in-place S
      }
    }
  }
  __syncthreads();   // S visible to all waves

  // ---- phase 5: ph = relu(S@Wc + D + cP); per-graph sum -> Sph (pad rows
  //      zeroed). fc rows crow,crow+1 match accD's col assignment.
  {
    const __bf16* Sb = Ab;
    #pragma unroll
    for (int kb = 0; kb < 128; kb += 32) {
      const int ko = kb + quad * 8;
      bf16x8 fa[4], fc[2];
      #pragma unroll
      for (int mt = 0; mt < 4; ++mt)
        fa[mt] = *(const bf16x8*)&Sb[(mt * 16 + l15) * LROW + ko];
      fc[0] = *(const bf16x8*)&WcT[(crow) * 128 + ko];
      fc[1] = *(const bf16x8*)&WcT[(crow + 1) * 128 + ko];
      #pragma unroll
      for (int mt = 0; mt < 4; ++mt) {
        accD[mt][0] = MFMA16(fa[mt], fc[0], accD[mt][0]);
        accD[mt][1] = MFMA16(fa[mt], fc[1], accD[mt][1]);
      }
    }
    const f32x2 cpv = *(const f32x2*)&vec[256 + crow];
    #pragma unroll
    for (int mt = 0; mt < 4; ++mt) {
      f32x4 a0 = accD[mt][0];
      f32x4 a1 = accD[mt][1];
      float s0 = fmaxf(a0[0] + cpv.x, 0.f) + fmaxf(a0[1] + cpv.x, 0.f)
               + fmaxf(a0[2] + cpv.x, 0.f) + fmaxf(a0[3] + cpv.x, 0.f);
      float s1 = fmaxf(a1[0] + cpv.y, 0.f) + fmaxf(a1[1] + cpv.y, 0.f)
               + fmaxf(a1[2] + cpv.y, 0.f) + fmaxf(a1[3] + cpv.y, 0.f);
      s0 += __shfl_xor(s0, 16);
      s1 += __shfl_xor(s1, 16);
      int grow = mt * 2 + (lane >= 32 ? 1 : 0);
      if ((lane & 31) < 16) {
        bf16x2v o = { (__bf16)s0, (__bf16)s1 };
        *(bf16x2v*)&Sph[grow * LROW + crow] = o;
      } else {
        *(unsigned*)&Sph[(8 + grow) * LROW + crow] = 0u;  // zero pad rows
      }
    }
  }
  __syncthreads();

  // ---- phase 6: ho = relu(Sph @ WO + cO)  (M=16 tile: 8 graphs + 8 zero rows)
  {
    f32x4 acco[2];
    f32x4 zero = {0.f, 0.f, 0.f, 0.f};
    acco[0] = zero; acco[1] = zero;
    #pragma unroll
    for (int kb = 0; kb < 128; kb += 32) {
      const int ko = kb + quad * 8;
      bf16x8 fa = *(const bf16x8*)&Sph[l15 * LROW + ko];
      bf16x8 fb0 = *(const bf16x8*)&WoT[(crow) * 128 + ko];
      bf16x8 fb1 = *(const bf16x8*)&WoT[(crow + 1) * 128 + ko];
      acco[0] = MFMA16(fa, fb0, acco[0]);
      acco[1] = MFMA16(fa, fb1, acco[1]);
    }
    const f32x2 cov = *(const f32x2*)&vec[384 + crow];
    #pragma unroll
    for (int r = 0; r < 4; ++r) {
      bf16x2v o = { (__bf16)fmaxf(acco[0][r] + cov.x, 0.f),
                    (__bf16)fmaxf(acco[1][r] + cov.y, 0.f) };
      *(bf16x2v*)&hob[(quad * 4 + r) * LROW + crow] = o;
    }
  }
  __syncthreads();

  // ---- phase 7: logits = ho @ out_W2 + out_b2  (wave 0 only) UNCHANGED
  if (w == 0) {
    f32x4 accf = {0.f, 0.f, 0.f, 0.f};
    #pragma unroll
    for (int kb = 0; kb < 128; kb += 32) {
      const int ko = kb + quad * 8;
      bf16x8 fa  = *(const bf16x8*)&hob[l15 * LROW + ko];
      bf16x8 fbv = *(const bf16x8*)&Wo2T[l15 * 128 + ko];
      accf = MFMA16(fa, fbv, accf);
    }
    if (quad < 2) {
      float b2 = out_b2[l15];
      #pragma unroll
      for (int r = 0; r < 4; ++r) {
        int row = quad * 4 + r;
        out[(g0 + row) * 16 + l15] = accf[r] + b2;
      }
    }
  }
}

extern "C" void kernel_launch(void* const* d_in, const int* in_sizes, int n_in,
                              void* d_out, int out_size, void* d_ws, size_t ws_size,
                              hipStream_t stream) {
  const int*   anchors   = (const int*)d_in[0];
  const int*   n_jumps   = (const int*)d_in[1];
  const float* positions = (const float*)d_in[2];
  const int*   colors    = (const int*)d_in[3];
  const int*   markers   = (const int*)d_in[4];
  const float* pre_W1  = (const float*)d_in[5];
  const float* pre_b1  = (const float*)d_in[6];
  const float* pre_W2  = (const float*)d_in[7];
  const float* pre_b2  = (const float*)d_in[8];
  const float* msg_W1  = (const float*)d_in[9];
  const float* msg_b1  = (const float*)d_in[10];
  const float* msg_W2  = (const float*)d_in[11];
  const float* msg_b2  = (const float*)d_in[12];
  const float* post_W1 = (const float*)d_in[13];
  const float* post_b1 = (const float*)d_in[14];
  const float* post_W2 = (const float*)d_in[15];
  const float* post_b2 = (const float*)d_in[16];
  const float* out_W1  = (const float*)d_in[17];
  const float* out_b1  = (const float*)d_in[18];
  const float* out_W2  = (const float*)d_in[19];
  const float* out_b2  = (const float*)d_in[20];

  char* ws = (char*)d_ws;
  unsigned short* WabT = (unsigned short*)(ws);            // [256][128] bf16
  unsigned short* WdT  = (unsigned short*)(ws + 65536);    // [128][128]
  unsigned short* WcT  = (unsigned short*)(ws + 98304);    // [128][128]
  unsigned short* WoT  = (unsigned short*)(ws + 131072);   // [128][128]
  unsigned short* Wo2T = (unsigned short*)(ws + 163840);   // [16][128]
  float*          vecs = (float*)(ws + 167936);            // 512 f32
  unsigned short* W1pT = (unsigned short*)(ws + 169984);   // [128][64] bf16

  const int BS = in_sizes[0];

  combine_weights<<<324, 256, 0, stream>>>(
      pre_W1, pre_b1, pre_W2, msg_W1, msg_W2, post_W1, post_W2, out_W1, out_W2,
      pre_b2, msg_b1, msg_b2, post_b1, post_b2, out_b1,
      WabT, WdT, WcT, WoT, Wo2T, W1pT, vecs);

  rrn_main<<<BS / 8, 256, 0, stream>>>(
      anchors, n_jumps, positions, colors, markers,
      (const __bf16*)W1pT,
      (const __bf16*)WabT, (const __bf16*)WdT, (const __bf16*)WcT,
      (const __bf16*)WoT, (const __bf16*)Wo2T, vecs, out_b2, (float*)d_out);
}